// Round 1
// baseline (994.364 us; speedup 1.0000x reference)
//
#include <hip/hip_runtime.h>
#include <math.h>

#define N_S   32768
#define K_C   2048
#define D_DIM 512
#define KD    (K_C * D_DIM)

#define TM    128
#define TK    128
#define DT    32
#define SPLIT 2
#define KPER  (K_C / SPLIT)   // 1024 clusters per block
#define NKT   (KPER / TK)     // 8 cluster tiles per block

// ---------------------------------------------------------------- row norms
__global__ void row_norms_kernel(const float* __restrict__ S, const float* __restrict__ M,
                                 float* __restrict__ snorm, float* __restrict__ mnorm) {
  int row  = blockIdx.x * 4 + (threadIdx.x >> 6);
  int lane = threadIdx.x & 63;
  if (row >= N_S + K_C) return;
  const float* src;
  float* dst;
  if (row < N_S) { src = S + (size_t)row * D_DIM; dst = snorm + row; }
  else { int r = row - N_S; src = M + (size_t)r * D_DIM; dst = mnorm + r; }
  float4 v0 = *(const float4*)(src + lane * 4);
  float4 v1 = *(const float4*)(src + 256 + lane * 4);
  float s = v0.x*v0.x + v0.y*v0.y + v0.z*v0.z + v0.w*v0.w
          + v1.x*v1.x + v1.y*v1.y + v1.z*v1.z + v1.w*v1.w;
  for (int off = 32; off; off >>= 1) s += __shfl_down(s, off);
  if (lane == 0) *dst = s;
}

// ------------------------------------------- fused distance GEMM + argmin
__launch_bounds__(256)
__global__ void dist_argmin_kernel(const float* __restrict__ S, const float* __restrict__ M,
                                   const float* __restrict__ mnorm,
                                   float* __restrict__ pval, int* __restrict__ pidx) {
  __shared__ float4 As[TM * DT / 4];   // 16 KiB, 16B-chunk XOR swizzled
  __shared__ float4 Bs[TK * DT / 4];   // 16 KiB
  const int t  = threadIdx.x;
  const int tx = t & 15;               // cluster dim
  const int ty = t >> 4;               // sample dim
  const int stile = blockIdx.x >> 1;
  const int split = blockIdx.x & 1;
  const int srow0 = stile * TM;
  const int kcol0 = split * KPER;

  float minv[8];
  int   mink[8];
#pragma unroll
  for (int i = 0; i < 8; ++i) { minv[i] = 3.4e38f; mink[i] = 0; }

  for (int kt = 0; kt < NKT; ++kt) {
    const int kbase = kcol0 + kt * TK;
    float acc[8][8];
#pragma unroll
    for (int i = 0; i < 8; ++i)
#pragma unroll
      for (int j = 0; j < 8; ++j) acc[i][j] = 0.f;

    for (int dt = 0; dt < D_DIM; dt += DT) {
      const float* Ag = S + (size_t)srow0 * D_DIM + dt;
      const float* Bg = M + (size_t)kbase * D_DIM + dt;
      __syncthreads();                 // protect LDS reuse from previous iter
#pragma unroll
      for (int q = 0; q < 4; ++q) {
        int id = t + q * 256;          // 0..1023 chunk id
        int r  = id >> 3, c = id & 7;
        int sw = r * 8 + (c ^ ((r >> 3) & 7));
        As[sw] = *(const float4*)(Ag + (size_t)r * D_DIM + c * 4);
        Bs[sw] = *(const float4*)(Bg + (size_t)r * D_DIM + c * 4);
      }
      __syncthreads();
#pragma unroll
      for (int c = 0; c < 8; ++c) {
        float4 a4[8], b4[8];
#pragma unroll
        for (int i = 0; i < 8; ++i) a4[i] = As[(ty * 8 + i) * 8 + (c ^ (ty & 7))];
#pragma unroll
        for (int j = 0; j < 8; ++j) b4[j] = Bs[(tx * 8 + j) * 8 + (c ^ (tx & 7))];
#pragma unroll
        for (int i = 0; i < 8; ++i)
#pragma unroll
          for (int j = 0; j < 8; ++j) {
            acc[i][j] += a4[i].x * b4[j].x;
            acc[i][j] += a4[i].y * b4[j].y;
            acc[i][j] += a4[i].z * b4[j].z;
            acc[i][j] += a4[i].w * b4[j].w;
          }
      }
    }
    // epilogue for this cluster tile: running argmin (k ascending, strict <)
#pragma unroll
    for (int j = 0; j < 8; ++j) {
      int k = kbase + tx * 8 + j;
      float mn = mnorm[k];
#pragma unroll
      for (int i = 0; i < 8; ++i) {
        float dval = mn - 2.f * acc[i][j];
        if (dval < minv[i]) { minv[i] = dval; mink[i] = k; }
      }
    }
  }

  // cross-thread (tx) reduction via LDS
  __syncthreads();
  float* rv = (float*)As;
  int*   ri = (int*)Bs;
#pragma unroll
  for (int i = 0; i < 8; ++i) {
    rv[(ty * 8 + i) * 16 + tx] = minv[i];
    ri[(ty * 8 + i) * 16 + tx] = mink[i];
  }
  __syncthreads();
  if (t < TM) {
    float best = rv[t * 16];
    int   bk   = ri[t * 16];
#pragma unroll
    for (int x = 1; x < 16; ++x) {
      float v = rv[t * 16 + x];
      int  k2 = ri[t * 16 + x];
      if (v < best || (v == best && k2 < bk)) { best = v; bk = k2; }
    }
    int n = srow0 + t;
    pval[(size_t)n * SPLIT + split] = best;
    pidx[n * SPLIT + split] = bk;
  }
}

// ------------------------------------------------- merge splits + inertia
__global__ void merge_bins_kernel(const float* __restrict__ pval, const int* __restrict__ pidx,
                                  const float* __restrict__ snorm,
                                  int* __restrict__ bins, float* __restrict__ inertia) {
  int n = blockIdx.x * 256 + threadIdx.x;
  float best = pval[(size_t)n * SPLIT];
  int   bk   = pidx[n * SPLIT];
#pragma unroll
  for (int s = 1; s < SPLIT; ++s) {
    float v = pval[(size_t)n * SPLIT + s];
    if (v < best) { best = v; bk = pidx[n * SPLIT + s]; }  // split1 k's all larger: strict < ok
  }
  bins[n] = bk;
  float dsel = snorm[n] + best;
  float r = sqrtf(fmaxf(dsel, 0.f));
  for (int off = 32; off; off >>= 1) r += __shfl_down(r, off);
  if ((threadIdx.x & 63) == 0) atomicAdd(inertia, r);
}

// ----------------------------------------------------- scatter cluster sums
__global__ void scatter_kernel(const float* __restrict__ S, const int* __restrict__ bins,
                               float* __restrict__ csum, float* __restrict__ counts) {
  int w    = (blockIdx.x * 256 + threadIdx.x) >> 6;  // one wave per sample
  int lane = threadIdx.x & 63;
  if (w >= N_S) return;
  int b = bins[w];
  const float* src = S + (size_t)w * D_DIM;
  float* dst = csum + (size_t)b * D_DIM;
#pragma unroll
  for (int c = 0; c < D_DIM; c += 64) atomicAdd(dst + c + lane, src[c + lane]);
  if (lane == 0) atomicAdd(counts + b, 1.0f);
}

// --------------------------------------------------------------- finalize
__global__ void finalize_kernel(const float* __restrict__ M, const float* __restrict__ W,
                                const float* __restrict__ counts, float* __restrict__ out) {
  int idx = blockIdx.x * 256 + threadIdx.x;
  int k = idx >> 9;
  float cnt = counts[k];
  float w   = W[k];
  float nw  = w + cnt;
  float alpha = 1.f / ((nw == 0.f) ? 1.f : nw);
  float m = M[idx];
  float v = (out[idx] + m * w) * alpha;
  out[idx] = (cnt == 0.f) ? m : v;
}

extern "C" void kernel_launch(void* const* d_in, const int* in_sizes, int n_in,
                              void* d_out, int out_size, void* d_ws, size_t ws_size,
                              hipStream_t stream) {
  const float* S = (const float*)d_in[0];
  const float* M = (const float*)d_in[1];
  const float* W = (const float*)d_in[2];
  float* out = (float*)d_out;

  float* ws     = (float*)d_ws;
  float* mnorm  = ws;                              // K
  float* snorm  = mnorm + K_C;                     // N
  int*   bins   = (int*)(snorm + N_S);             // N
  float* counts = (float*)(bins + N_S);            // K
  float* pval   = counts + K_C;                    // N*SPLIT
  int*   pidx   = (int*)(pval + (size_t)N_S * SPLIT); // N*SPLIT

  hipMemsetAsync(d_out, 0, (size_t)(KD + 1) * sizeof(float), stream); // csum + inertia accumulator
  hipMemsetAsync(counts, 0, K_C * sizeof(float), stream);

  row_norms_kernel<<<(N_S + K_C) / 4, 256, 0, stream>>>(S, M, snorm, mnorm);
  dist_argmin_kernel<<<(N_S / TM) * SPLIT, 256, 0, stream>>>(S, M, mnorm, pval, pidx);
  merge_bins_kernel<<<N_S / 256, 256, 0, stream>>>(pval, pidx, snorm, bins, out + KD);
  scatter_kernel<<<N_S / 4, 256, 0, stream>>>(S, bins, out, counts);
  finalize_kernel<<<KD / 256, 256, 0, stream>>>(M, W, counts, out);
}

// Round 2
// 903.744 us; speedup vs baseline: 1.1003x; 1.1003x over previous
//
#include <hip/hip_runtime.h>
#include <hip/hip_bf16.h>
#include <math.h>
#include <float.h>

#define N_S   32768
#define K_C   2048
#define D_DIM 512
#define KD    (K_C * D_DIM)

#define TM    128          // samples per tile
#define TKT   128          // clusters per tile
#define BK    32           // D-chunk
#define SPLIT 2
#define KPER  (K_C / SPLIT)
#define NKT   (KPER / TKT) // cluster tiles per block
#define NDT   (D_DIM / BK) // D steps
#define MARGIN 0.25f

using s16x8 = __attribute__((ext_vector_type(8))) short;
using f32x4 = __attribute__((ext_vector_type(4))) float;

__device__ inline void cvt_hl(float x, ushort& hb, ushort& lb) {
  __hip_bfloat16 h = __float2bfloat16(x);
  hb = *reinterpret_cast<ushort*>(&h);
  float hf = __bfloat162float(h);
  __hip_bfloat16 l = __float2bfloat16(x - hf);
  lb = *reinterpret_cast<ushort*>(&l);
}

__device__ inline void top2_merge(float& a1, int& ai, float& a2, float b1, int bi, float b2) {
  if (b1 < a1 || (b1 == a1 && bi < ai)) { a2 = fminf(a1, b2); a1 = b1; ai = bi; }
  else { a2 = fminf(a2, b1); }
}

// ---------------------------------------------------------------- row norms
__global__ void row_norms_kernel(const float* __restrict__ S, const float* __restrict__ M,
                                 float* __restrict__ snorm, float* __restrict__ mnorm) {
  int row  = blockIdx.x * 4 + (threadIdx.x >> 6);
  int lane = threadIdx.x & 63;
  if (row >= N_S + K_C) return;
  const float* src;
  float* dst;
  if (row < N_S) { src = S + (size_t)row * D_DIM; dst = snorm + row; }
  else { int r = row - N_S; src = M + (size_t)r * D_DIM; dst = mnorm + r; }
  float4 v0 = *(const float4*)(src + lane * 4);
  float4 v1 = *(const float4*)(src + 256 + lane * 4);
  float s = v0.x*v0.x + v0.y*v0.y + v0.z*v0.z + v0.w*v0.w
          + v1.x*v1.x + v1.y*v1.y + v1.z*v1.z + v1.w*v1.w;
  for (int off = 32; off; off >>= 1) s += __shfl_down(s, off);
  if (lane == 0) *dst = s;
}

// --------------------------- fused split-bf16 MFMA distance GEMM + top-2 argmin
__launch_bounds__(256)
__global__ void dist_argmin_kernel(const float* __restrict__ S, const float* __restrict__ M,
                                   const float* __restrict__ mnorm,
                                   float* __restrict__ pval, int* __restrict__ pidx,
                                   float* __restrict__ pm2) {
  // tiles[buf][ {A_hi, A_lo, B_hi, B_lo} ][128*32] bf16 bits
  __shared__ ushort tiles[2][4][TM * BK];
  __shared__ float sm1[TM * 2];
  __shared__ float sm2[TM * 2];
  __shared__ int   si1[TM * 2];

  const int t    = threadIdx.x;
  const int lane = t & 63, wid = t >> 6;
  const int wr   = wid >> 1, wc = wid & 1;
  const int lx   = lane & 15, kg = lane >> 4;
  const int stile = blockIdx.x >> 1, split = blockIdx.x & 1;
  const int srow0 = stile * TM;
  const int kcol0 = split * KPER;

  for (int i = t; i < TM * 2; i += 256) { sm1[i] = FLT_MAX; sm2[i] = FLT_MAX; si1[i] = 0; }

  float4 av[4], bv[4];

#define LOADREGS(dtoff) do { \
    const float* Ag = S + (size_t)srow0 * D_DIM + (dtoff); \
    const float* Bg = M + (size_t)kbase * D_DIM + (dtoff); \
    _Pragma("unroll") \
    for (int q = 0; q < 4; ++q) { \
      int id = t + q * 256; int r_ = id >> 3, c_ = (id & 7) * 4; \
      av[q] = *(const float4*)(Ag + (size_t)r_ * D_DIM + c_); \
      bv[q] = *(const float4*)(Bg + (size_t)r_ * D_DIM + c_); \
    } } while (0)

#define WRITETILE(buf) do { \
    _Pragma("unroll") \
    for (int q = 0; q < 4; ++q) { \
      int id = t + q * 256; int r_ = id >> 3, c_ = (id & 7) * 4; \
      ushort4 h4, l4; \
      cvt_hl(av[q].x, h4.x, l4.x); cvt_hl(av[q].y, h4.y, l4.y); \
      cvt_hl(av[q].z, h4.z, l4.z); cvt_hl(av[q].w, h4.w, l4.w); \
      *(ushort4*)&tiles[buf][0][r_ * BK + c_] = h4; \
      *(ushort4*)&tiles[buf][1][r_ * BK + c_] = l4; \
      cvt_hl(bv[q].x, h4.x, l4.x); cvt_hl(bv[q].y, h4.y, l4.y); \
      cvt_hl(bv[q].z, h4.z, l4.z); cvt_hl(bv[q].w, h4.w, l4.w); \
      *(ushort4*)&tiles[buf][2][r_ * BK + c_] = h4; \
      *(ushort4*)&tiles[buf][3][r_ * BK + c_] = l4; \
    } } while (0)

  for (int kt = 0; kt < NKT; ++kt) {
    const int kbase = kcol0 + kt * TKT;
    f32x4 acc[4][4];
#pragma unroll
    for (int i = 0; i < 4; ++i)
#pragma unroll
      for (int j = 0; j < 4; ++j) { acc[i][j][0] = 0.f; acc[i][j][1] = 0.f; acc[i][j][2] = 0.f; acc[i][j][3] = 0.f; }

    float mn[4];
#pragma unroll
    for (int ni = 0; ni < 4; ++ni) mn[ni] = mnorm[kbase + wc * 64 + ni * 16 + lx];

    LOADREGS(0);
    WRITETILE(0);
    __syncthreads();

    for (int di = 0; di < NDT; ++di) {
      const int cur = di & 1;
      if (di + 1 < NDT) LOADREGS((di + 1) * BK);
      {
        s16x8 ah[4], al[4], bh[4], bl[4];
#pragma unroll
        for (int i = 0; i < 4; ++i) {
          ah[i] = *(const s16x8*)&tiles[cur][0][(wr * 64 + i * 16 + lx) * BK + kg * 8];
          al[i] = *(const s16x8*)&tiles[cur][1][(wr * 64 + i * 16 + lx) * BK + kg * 8];
          bh[i] = *(const s16x8*)&tiles[cur][2][(wc * 64 + i * 16 + lx) * BK + kg * 8];
          bl[i] = *(const s16x8*)&tiles[cur][3][(wc * 64 + i * 16 + lx) * BK + kg * 8];
        }
#pragma unroll
        for (int i = 0; i < 4; ++i)
#pragma unroll
          for (int j = 0; j < 4; ++j) {
            acc[i][j] = __builtin_amdgcn_mfma_f32_16x16x32_bf16(ah[i], bh[j], acc[i][j], 0, 0, 0);
            acc[i][j] = __builtin_amdgcn_mfma_f32_16x16x32_bf16(ah[i], bl[j], acc[i][j], 0, 0, 0);
            acc[i][j] = __builtin_amdgcn_mfma_f32_16x16x32_bf16(al[i], bh[j], acc[i][j], 0, 0, 0);
          }
      }
      if (di + 1 < NDT) {
        WRITETILE(cur ^ 1);
        __syncthreads();
      }
    }

    // epilogue: per-row top-2 over this cluster tile, merged into LDS state
#pragma unroll
    for (int mi = 0; mi < 4; ++mi)
#pragma unroll
      for (int r = 0; r < 4; ++r) {
        float v1 = FLT_MAX, v2 = FLT_MAX; int i1 = 0;
#pragma unroll
        for (int ni = 0; ni < 4; ++ni) {
          float v = mn[ni] - 2.f * acc[mi][ni][r];
          int k = kbase + wc * 64 + ni * 16 + lx;
          if (v < v1) { v2 = v1; v1 = v; i1 = k; } else { v2 = fminf(v2, v); }
        }
#pragma unroll
        for (int msk = 1; msk < 16; msk <<= 1) {
          float o1 = __shfl_xor(v1, msk);
          int   oi = __shfl_xor(i1, msk);
          float o2 = __shfl_xor(v2, msk);
          top2_merge(v1, i1, v2, o1, oi, o2);
        }
        if (lx == 0) {
          int row = wr * 64 + mi * 16 + kg * 4 + r;
          int s = row * 2 + wc;
          float a1 = sm1[s], a2 = sm2[s]; int ai = si1[s];
          top2_merge(a1, ai, a2, v1, i1, v2);
          sm1[s] = a1; sm2[s] = a2; si1[s] = ai;
        }
      }
  }

  __syncthreads();
  if (t < TM) {
    float a1 = sm1[t * 2], a2 = sm2[t * 2]; int ai = si1[t * 2];
    top2_merge(a1, ai, a2, sm1[t * 2 + 1], si1[t * 2 + 1], sm2[t * 2 + 1]);
    int n = srow0 + t;
    pval[n * SPLIT + split] = a1;
    pidx[n * SPLIT + split] = ai;
    pm2[n * SPLIT + split]  = a2;
  }
#undef LOADREGS
#undef WRITETILE
}

// ------------------------------- merge splits, flag ambiguous, inertia (unflagged)
__global__ void merge_bins_kernel(const float* __restrict__ pval, const int* __restrict__ pidx,
                                  const float* __restrict__ pm2, const float* __restrict__ snorm,
                                  int* __restrict__ bins, float* __restrict__ inertia,
                                  int* __restrict__ flag_list, int* __restrict__ flag_count) {
  int n = blockIdx.x * 256 + threadIdx.x;
  float a1 = pval[n * SPLIT], a2 = pm2[n * SPLIT]; int ai = pidx[n * SPLIT];
  top2_merge(a1, ai, a2, pval[n * SPLIT + 1], pidx[n * SPLIT + 1], pm2[n * SPLIT + 1]);
  float r = 0.f;
  if (a2 - a1 <= MARGIN) {
    int idx = atomicAdd(flag_count, 1);
    flag_list[idx] = n;
  } else {
    bins[n] = ai;
    r = sqrtf(fmaxf(snorm[n] + a1, 0.f));
  }
  for (int off = 32; off; off >>= 1) r += __shfl_down(r, off);
  if ((threadIdx.x & 63) == 0) atomicAdd(inertia, r);
}

// ------------------------------- exact fp32 re-resolve for flagged samples
__launch_bounds__(256)
__global__ void cleanup_kernel(const float* __restrict__ S, const float* __restrict__ M,
                               const float* __restrict__ snorm, const float* __restrict__ mnorm,
                               const int* __restrict__ flag_list, const int* __restrict__ flag_count,
                               int* __restrict__ bins, float* __restrict__ inertia) {
  __shared__ float sS[D_DIM];
  __shared__ float wv[4];
  __shared__ int   wk[4];
  const int t = threadIdx.x, lane = t & 63, wid = t >> 6;
  const int cnt = *flag_count;
  for (int fi = blockIdx.x; fi < cnt; fi += gridDim.x) {
    int n = flag_list[fi];
    __syncthreads();
    for (int i = t; i < D_DIM; i += 256) sS[i] = S[(size_t)n * D_DIM + i];
    __syncthreads();
    float best = FLT_MAX; int bk = 0;
    for (int k = wid; k < K_C; k += 4) {
      const float* mr = M + (size_t)k * D_DIM;
      float4 m0 = *(const float4*)(mr + lane * 8);
      float4 m1 = *(const float4*)(mr + lane * 8 + 4);
      float4 s0 = *(const float4*)(sS + lane * 8);
      float4 s1 = *(const float4*)(sS + lane * 8 + 4);
      float p = m0.x*s0.x + m0.y*s0.y + m0.z*s0.z + m0.w*s0.w
              + m1.x*s1.x + m1.y*s1.y + m1.z*s1.z + m1.w*s1.w;
      for (int msk = 1; msk < 64; msk <<= 1) p += __shfl_xor(p, msk);
      float dist = mnorm[k] - 2.f * p;
      if (dist < best) { best = dist; bk = k; }   // k ascending within wave: lowest-idx tie-break
    }
    if (lane == 0) { wv[wid] = best; wk[wid] = bk; }
    __syncthreads();
    if (t == 0) {
      float b = wv[0]; int bi = wk[0];
      for (int w = 1; w < 4; ++w)
        if (wv[w] < b || (wv[w] == b && wk[w] < bi)) { b = wv[w]; bi = wk[w]; }
      bins[n] = bi;
      atomicAdd(inertia, sqrtf(fmaxf(snorm[n] + b, 0.f)));
    }
  }
}

// ----------------------------------------------------- scatter cluster sums
__global__ void scatter_kernel(const float* __restrict__ S, const int* __restrict__ bins,
                               float* __restrict__ csum, float* __restrict__ counts) {
  int w    = (blockIdx.x * 256 + threadIdx.x) >> 6;
  int lane = threadIdx.x & 63;
  if (w >= N_S) return;
  int b = bins[w];
  const float* src = S + (size_t)w * D_DIM;
  float* dst = csum + (size_t)b * D_DIM;
#pragma unroll
  for (int c = 0; c < D_DIM; c += 64) atomicAdd(dst + c + lane, src[c + lane]);
  if (lane == 0) atomicAdd(counts + b, 1.0f);
}

// --------------------------------------------------------------- finalize
__global__ void finalize_kernel(const float* __restrict__ M, const float* __restrict__ W,
                                const float* __restrict__ counts, float* __restrict__ out) {
  int idx = blockIdx.x * 256 + threadIdx.x;
  int k = idx >> 9;
  float cnt = counts[k];
  float w   = W[k];
  float nw  = w + cnt;
  float alpha = 1.f / ((nw == 0.f) ? 1.f : nw);
  float m = M[idx];
  float v = (out[idx] + m * w) * alpha;
  out[idx] = (cnt == 0.f) ? m : v;
}

extern "C" void kernel_launch(void* const* d_in, const int* in_sizes, int n_in,
                              void* d_out, int out_size, void* d_ws, size_t ws_size,
                              hipStream_t stream) {
  const float* S = (const float*)d_in[0];
  const float* M = (const float*)d_in[1];
  const float* W = (const float*)d_in[2];
  float* out = (float*)d_out;

  float* ws        = (float*)d_ws;
  float* mnorm     = ws;                               // K
  float* snorm     = mnorm + K_C;                      // N
  int*   bins      = (int*)(snorm + N_S);              // N
  float* counts    = (float*)(bins + N_S);             // K
  float* pval      = counts + K_C;                     // N*2
  int*   pidx      = (int*)(pval + (size_t)N_S * 2);   // N*2
  float* pm2       = (float*)(pidx + (size_t)N_S * 2); // N*2
  int*   flag_count= (int*)(pm2 + (size_t)N_S * 2);    // 16 (padded)
  int*   flag_list = flag_count + 16;                  // N

  hipMemsetAsync(d_out, 0, (size_t)(KD + 1) * sizeof(float), stream);
  hipMemsetAsync(counts, 0, K_C * sizeof(float), stream);
  hipMemsetAsync(flag_count, 0, sizeof(int), stream);

  row_norms_kernel<<<(N_S + K_C) / 4, 256, 0, stream>>>(S, M, snorm, mnorm);
  dist_argmin_kernel<<<(N_S / TM) * SPLIT, 256, 0, stream>>>(S, M, mnorm, pval, pidx, pm2);
  merge_bins_kernel<<<N_S / 256, 256, 0, stream>>>(pval, pidx, pm2, snorm, bins, out + KD,
                                                   flag_list, flag_count);
  cleanup_kernel<<<1024, 256, 0, stream>>>(S, M, snorm, mnorm, flag_list, flag_count,
                                           bins, out + KD);
  scatter_kernel<<<N_S / 4, 256, 0, stream>>>(S, bins, out, counts);
  finalize_kernel<<<KD / 256, 256, 0, stream>>>(M, W, counts, out);
}

// Round 3
// 700.724 us; speedup vs baseline: 1.4191x; 1.2897x over previous
//
#include <hip/hip_runtime.h>
#include <hip/hip_bf16.h>
#include <math.h>
#include <float.h>

#define N_S   32768
#define K_C   2048
#define D_DIM 512
#define KD    (K_C * D_DIM)
#define MARGIN 0.0625f

using s16x8 = __attribute__((ext_vector_type(8))) short;
using f32x4 = __attribute__((ext_vector_type(4))) float;

typedef const __attribute__((address_space(1))) unsigned int glb_u32_t;
typedef __attribute__((address_space(3))) unsigned int lds_u32_t;

__device__ __forceinline__ void gll16(const void* g, void* l) {
  __builtin_amdgcn_global_load_lds((glb_u32_t*)g, (lds_u32_t*)l, 16, 0, 0);
}

__device__ inline void cvt_hl(float x, ushort& hb, ushort& lb) {
  __hip_bfloat16 h = __float2bfloat16(x);
  hb = *reinterpret_cast<ushort*>(&h);
  float hf = __bfloat162float(h);
  __hip_bfloat16 l = __float2bfloat16(x - hf);
  lb = *reinterpret_cast<ushort*>(&l);
}

__device__ inline void top2_merge(float& a1, int& ai, float& a2, float b1, int bi, float b2) {
  if (b1 < a1 || (b1 == a1 && bi < ai)) { a2 = fminf(a1, b2); a1 = b1; ai = bi; }
  else { a2 = fminf(a2, b1); }
}

// ================================================================ FAST PATH

// Convert fp32 -> (hi, lo) bf16, pre-tiled+swizzled for the GEMM; fused row norms.
// Layout: Aq[tile(=row/128)*16 + kc][r(128)][64 bf16], kc 0..7 = hi d-chunks, 8..15 = lo.
// Within a tile row, 16B chunk c stored at (c ^ (r&7)).
__global__ void preconvert_kernel(const float* __restrict__ S, const float* __restrict__ M,
                                  ushort* __restrict__ Aq, ushort* __restrict__ Bq,
                                  float* __restrict__ snorm, float* __restrict__ mnorm) {
  int row = blockIdx.x * 4 + (threadIdx.x >> 6);
  int l   = threadIdx.x & 63;
  bool isS = row < N_S;
  int lr = isS ? row : row - N_S;
  const float* src = (isS ? S : M) + (size_t)lr * D_DIM + l * 8;
  float4 u0 = *(const float4*)(src);
  float4 u1 = *(const float4*)(src + 4);
  float x[8] = {u0.x, u0.y, u0.z, u0.w, u1.x, u1.y, u1.z, u1.w};
  s16x8 hv, lv;
  float nrm = 0.f;
#pragma unroll
  for (int i = 0; i < 8; ++i) {
    nrm += x[i] * x[i];
    ushort hb, lb;
    cvt_hl(x[i], hb, lb);
    hv[i] = (short)hb; lv[i] = (short)lb;
  }
  int r = lr & 127, tile = lr >> 7;
  int kc = l >> 3, slot = (l & 7) ^ (r & 7);
  ushort* dst = isS ? Aq : Bq;
  size_t basehi = ((size_t)(tile * 16 + kc)     * 128 + r) * 64 + slot * 8;
  size_t baselo = ((size_t)(tile * 16 + 8 + kc) * 128 + r) * 64 + slot * 8;
  *(s16x8*)(dst + basehi) = hv;
  *(s16x8*)(dst + baselo) = lv;
  for (int off = 32; off; off >>= 1) nrm += __shfl_down(nrm, off);
  if (l == 0) { if (isS) snorm[lr] = nrm; else mnorm[lr] = nrm; }
}

// 128x128 tile bf16-split GEMM (-2*S.M part) + fused per-row top-2 partials.
__launch_bounds__(256, 3)
__global__ void gemm_top2_kernel(const ushort* __restrict__ Aq, const ushort* __restrict__ Bq,
                                 const float* __restrict__ mnorm,
                                 float* __restrict__ pval, int* __restrict__ pidx,
                                 float* __restrict__ pm2) {
  __shared__ __align__(16) ushort lA[128 * 64];   // 16 KiB
  __shared__ __align__(16) ushort lB[128 * 64];   // 16 KiB
  __shared__ float rv1[128 * 2], rv2[128 * 2];
  __shared__ int   ri1[128 * 2];
  const int t = threadIdx.x, lane = t & 63, wid = t >> 6;
  const int wr = wid >> 1, wc = wid & 1;
  const int lx = lane & 15, kg = lane >> 4;
  // XCD-chunked swizzle: 4096 blocks, 8 XCDs -> each XCD owns 32 consecutive row-tiles
  int bid = ((int)blockIdx.x & 7) * 512 + ((int)blockIdx.x >> 3);
  const int rt = bid >> 4, ct = bid & 15;

  f32x4 acc[4][4];
#pragma unroll
  for (int i = 0; i < 4; ++i)
#pragma unroll
    for (int j = 0; j < 4; ++j) { acc[i][j][0] = 0.f; acc[i][j][1] = 0.f; acc[i][j][2] = 0.f; acc[i][j][3] = 0.f; }

  for (int s = 0; s < 24; ++s) {
    // term schedule: s 0..7 Ah*Bh, 8..15 Ah*Bl, 16..23 Al*Bh  (d-chunks aligned)
    int akc = (s < 16) ? (s & 7) : (s - 8);
    int bkc = s & 15;
    const char* ga = (const char*)(Aq + ((size_t)(rt * 16 + akc) << 13));
    const char* gb = (const char*)(Bq + ((size_t)(ct * 16 + bkc) << 13));
    __syncthreads();            // previous tile fully consumed
#pragma unroll
    for (int q = 0; q < 4; ++q) {
      gll16(ga + wid * 1024 + lane * 16 + q * 4096, (char*)lA + wid * 1024 + q * 4096);
      gll16(gb + wid * 1024 + lane * 16 + q * 4096, (char*)lB + wid * 1024 + q * 4096);
    }
    __syncthreads();            // staged (compiler drains vmcnt here)
#pragma unroll
    for (int kk = 0; kk < 2; ++kk) {
      s16x8 af[4], bf[4];
#pragma unroll
      for (int i = 0; i < 4; ++i) {
        int r = wr * 64 + i * 16 + lx;
        af[i] = *(const s16x8*)&lA[r * 64 + (((kk * 4 + kg) ^ (lx & 7)) * 8)];
      }
#pragma unroll
      for (int j = 0; j < 4; ++j) {
        int r = wc * 64 + j * 16 + lx;
        bf[j] = *(const s16x8*)&lB[r * 64 + (((kk * 4 + kg) ^ (lx & 7)) * 8)];
      }
#pragma unroll
      for (int i = 0; i < 4; ++i)
#pragma unroll
        for (int j = 0; j < 4; ++j)
          acc[i][j] = __builtin_amdgcn_mfma_f32_16x16x32_bf16(af[i], bf[j], acc[i][j], 0, 0, 0);
    }
  }

  // epilogue: dval = mnorm - 2*dot ; per-row top-2 over this block's 128 cols
  float mn[4];
#pragma unroll
  for (int j = 0; j < 4; ++j) mn[j] = mnorm[ct * 128 + wc * 64 + j * 16 + lx];
#pragma unroll
  for (int i = 0; i < 4; ++i)
#pragma unroll
    for (int reg = 0; reg < 4; ++reg) {
      float v1 = FLT_MAX, v2 = FLT_MAX; int i1 = 0;
#pragma unroll
      for (int j = 0; j < 4; ++j) {                 // j ascending => k ascending
        float v = mn[j] - 2.f * acc[i][j][reg];
        int k = ct * 128 + wc * 64 + j * 16 + lx;
        if (v < v1) { v2 = v1; v1 = v; i1 = k; } else v2 = fminf(v2, v);
      }
#pragma unroll
      for (int msk = 1; msk < 16; msk <<= 1) {
        float o1 = __shfl_xor(v1, msk);
        int   oi = __shfl_xor(i1, msk);
        float o2 = __shfl_xor(v2, msk);
        top2_merge(v1, i1, v2, o1, oi, o2);
      }
      if (lx == 0) {
        int rowr = wr * 64 + i * 16 + kg * 4 + reg;
        rv1[rowr * 2 + wc] = v1; ri1[rowr * 2 + wc] = i1; rv2[rowr * 2 + wc] = v2;
      }
    }
  __syncthreads();
  if (t < 128) {
    float a1 = rv1[t * 2], a2 = rv2[t * 2]; int ai = ri1[t * 2];
    top2_merge(a1, ai, a2, rv1[t * 2 + 1], ri1[t * 2 + 1], rv2[t * 2 + 1]);
    size_t n = (size_t)rt * 128 + t;
    pval[n * 16 + ct] = a1;
    pidx[n * 16 + ct] = ai;
    pm2 [n * 16 + ct] = a2;
  }
}

// merge 16 col-tile partials per row; flag ambiguous; count + inertia for sure rows
__global__ void merge2_kernel(const float* __restrict__ pval, const int* __restrict__ pidx,
                              const float* __restrict__ pm2, const float* __restrict__ snorm,
                              int* __restrict__ bins, float* __restrict__ inertia,
                              int* __restrict__ counts,
                              int* __restrict__ flag_list, int* __restrict__ flag_count) {
  int n = blockIdx.x * 256 + threadIdx.x;
  float a1 = FLT_MAX, a2 = FLT_MAX; int ai = 0x7fffffff;
  for (int c = 0; c < 16; ++c)                      // ct ascending => k ascending
    top2_merge(a1, ai, a2, pval[(size_t)n * 16 + c], pidx[(size_t)n * 16 + c], pm2[(size_t)n * 16 + c]);
  float r = 0.f;
  if (a2 - a1 <= MARGIN) {
    int idx = atomicAdd(flag_count, 1);
    flag_list[idx] = n;
  } else {
    bins[n] = ai;
    atomicAdd(&counts[ai], 1);
    r = sqrtf(fmaxf(snorm[n] + a1, 0.f));
  }
  for (int off = 32; off; off >>= 1) r += __shfl_down(r, off);
  if ((threadIdx.x & 63) == 0) atomicAdd(inertia, r);
}

// exact fp32 re-resolve for flagged samples
template <bool ADDCOUNT>
__launch_bounds__(256)
__global__ void cleanup_kernel(const float* __restrict__ S, const float* __restrict__ M,
                               const float* __restrict__ snorm, const float* __restrict__ mnorm,
                               const int* __restrict__ flag_list, const int* __restrict__ flag_count,
                               int* __restrict__ bins, float* __restrict__ inertia,
                               int* __restrict__ counts) {
  __shared__ float sS[D_DIM];
  __shared__ float wv[4];
  __shared__ int   wk[4];
  const int t = threadIdx.x, lane = t & 63, wid = t >> 6;
  const int cnt = *flag_count;
  for (int fi = blockIdx.x; fi < cnt; fi += gridDim.x) {
    int n = flag_list[fi];
    __syncthreads();
    for (int i = t; i < D_DIM; i += 256) sS[i] = S[(size_t)n * D_DIM + i];
    __syncthreads();
    float best = FLT_MAX; int bk = 0;
    for (int k = wid; k < K_C; k += 4) {
      const float* mr = M + (size_t)k * D_DIM;
      float4 m0 = *(const float4*)(mr + lane * 8);
      float4 m1 = *(const float4*)(mr + lane * 8 + 4);
      float4 s0 = *(const float4*)(sS + lane * 8);
      float4 s1 = *(const float4*)(sS + lane * 8 + 4);
      float p = m0.x*s0.x + m0.y*s0.y + m0.z*s0.z + m0.w*s0.w
              + m1.x*s1.x + m1.y*s1.y + m1.z*s1.z + m1.w*s1.w;
      for (int msk = 1; msk < 64; msk <<= 1) p += __shfl_xor(p, msk);
      float dist = mnorm[k] - 2.f * p;
      if (dist < best) { best = dist; bk = k; }
    }
    if (lane == 0) { wv[wid] = best; wk[wid] = bk; }
    __syncthreads();
    if (t == 0) {
      float b = wv[0]; int bi = wk[0];
      for (int w = 1; w < 4; ++w)
        if (wv[w] < b || (wv[w] == b && wk[w] < bi)) { b = wv[w]; bi = wk[w]; }
      bins[n] = bi;
      if (ADDCOUNT) atomicAdd(&counts[bi], 1);
      atomicAdd(inertia, sqrtf(fmaxf(snorm[n] + b, 0.f)));
    }
  }
}

// exclusive prefix sum over 2048 counts (single block)
__global__ void prefix_kernel(const int* __restrict__ counts, int* __restrict__ starts,
                              int* __restrict__ cursor) {
  __shared__ int part[256];
  int t = threadIdx.x;
  int loc[8]; int s = 0;
#pragma unroll
  for (int i = 0; i < 8; ++i) { loc[i] = s; s += counts[t * 8 + i]; }
  part[t] = s;
  __syncthreads();
  for (int off = 1; off < 256; off <<= 1) {
    int v = (t >= off) ? part[t - off] : 0;
    __syncthreads();
    part[t] += v;
    __syncthreads();
  }
  int base = (t == 0) ? 0 : part[t - 1];
#pragma unroll
  for (int i = 0; i < 8; ++i) { starts[t * 8 + i] = base + loc[i]; cursor[t * 8 + i] = base + loc[i]; }
}

__global__ void fill_kernel(const int* __restrict__ bins, int* __restrict__ cursor,
                            int* __restrict__ bucket) {
  int n = blockIdx.x * 256 + threadIdx.x;
  int pos = atomicAdd(&cursor[bins[n]], 1);
  bucket[pos] = n;
}

// per-cluster gather of assigned samples + finalize new_means (no atomics)
__global__ void gather_finalize_kernel(const float* __restrict__ S, const float* __restrict__ M,
                                       const float* __restrict__ W,
                                       const int* __restrict__ starts, const int* __restrict__ counts,
                                       const int* __restrict__ bucket, float* __restrict__ out) {
  int k = blockIdx.x, t = threadIdx.x;
  int cnt = counts[k], s0 = starts[k];
  float acc0 = 0.f, acc1 = 0.f;
  for (int i = 0; i < cnt; ++i) {
    const float* row = S + (size_t)bucket[s0 + i] * D_DIM;
    acc0 += row[t];
    acc1 += row[t + 256];
  }
  float w = W[k];
  float nw = w + (float)cnt;
  float alpha = 1.f / ((nw == 0.f) ? 1.f : nw);
  size_t o = (size_t)k * D_DIM + t;
  float m0 = M[o], m1 = M[o + 256];
  out[o]       = (cnt == 0) ? m0 : (acc0 + m0 * w) * alpha;
  out[o + 256] = (cnt == 0) ? m1 : (acc1 + m1 * w) * alpha;
}

// ============================================================ FALLBACK PATH (round-2, passes @904us)

#define TM    128
#define BK2   32
#define SPLIT 2
#define KPER  (K_C / SPLIT)
#define NKT   (KPER / TM)
#define NDT   (D_DIM / BK2)

__global__ void row_norms_kernel(const float* __restrict__ S, const float* __restrict__ M,
                                 float* __restrict__ snorm, float* __restrict__ mnorm) {
  int row  = blockIdx.x * 4 + (threadIdx.x >> 6);
  int lane = threadIdx.x & 63;
  if (row >= N_S + K_C) return;
  const float* src;
  float* dst;
  if (row < N_S) { src = S + (size_t)row * D_DIM; dst = snorm + row; }
  else { int r = row - N_S; src = M + (size_t)r * D_DIM; dst = mnorm + r; }
  float4 v0 = *(const float4*)(src + lane * 4);
  float4 v1 = *(const float4*)(src + 256 + lane * 4);
  float s = v0.x*v0.x + v0.y*v0.y + v0.z*v0.z + v0.w*v0.w
          + v1.x*v1.x + v1.y*v1.y + v1.z*v1.z + v1.w*v1.w;
  for (int off = 32; off; off >>= 1) s += __shfl_down(s, off);
  if (lane == 0) *dst = s;
}

__launch_bounds__(256)
__global__ void dist_argmin_kernel(const float* __restrict__ S, const float* __restrict__ M,
                                   const float* __restrict__ mnorm,
                                   float* __restrict__ pval, int* __restrict__ pidx,
                                   float* __restrict__ pm2) {
  __shared__ ushort tiles[2][4][TM * BK2];
  __shared__ float sm1[TM * 2];
  __shared__ float sm2[TM * 2];
  __shared__ int   si1[TM * 2];
  const int t    = threadIdx.x;
  const int lane = t & 63, wid = t >> 6;
  const int wr   = wid >> 1, wc = wid & 1;
  const int lx   = lane & 15, kg = lane >> 4;
  const int stile = blockIdx.x >> 1, split = blockIdx.x & 1;
  const int srow0 = stile * TM;
  const int kcol0 = split * KPER;
  for (int i = t; i < TM * 2; i += 256) { sm1[i] = FLT_MAX; sm2[i] = FLT_MAX; si1[i] = 0; }
  float4 av[4], bv[4];
#define LOADREGS(dtoff) do { \
    const float* Ag = S + (size_t)srow0 * D_DIM + (dtoff); \
    const float* Bg = M + (size_t)kbase * D_DIM + (dtoff); \
    _Pragma("unroll") \
    for (int q = 0; q < 4; ++q) { \
      int id = t + q * 256; int r_ = id >> 3, c_ = (id & 7) * 4; \
      av[q] = *(const float4*)(Ag + (size_t)r_ * D_DIM + c_); \
      bv[q] = *(const float4*)(Bg + (size_t)r_ * D_DIM + c_); \
    } } while (0)
#define WRITETILE(buf) do { \
    _Pragma("unroll") \
    for (int q = 0; q < 4; ++q) { \
      int id = t + q * 256; int r_ = id >> 3, c_ = (id & 7) * 4; \
      ushort4 h4, l4; \
      cvt_hl(av[q].x, h4.x, l4.x); cvt_hl(av[q].y, h4.y, l4.y); \
      cvt_hl(av[q].z, h4.z, l4.z); cvt_hl(av[q].w, h4.w, l4.w); \
      *(ushort4*)&tiles[buf][0][r_ * BK2 + c_] = h4; \
      *(ushort4*)&tiles[buf][1][r_ * BK2 + c_] = l4; \
      cvt_hl(bv[q].x, h4.x, l4.x); cvt_hl(bv[q].y, h4.y, l4.y); \
      cvt_hl(bv[q].z, h4.z, l4.z); cvt_hl(bv[q].w, h4.w, l4.w); \
      *(ushort4*)&tiles[buf][2][r_ * BK2 + c_] = h4; \
      *(ushort4*)&tiles[buf][3][r_ * BK2 + c_] = l4; \
    } } while (0)
  for (int kt = 0; kt < NKT; ++kt) {
    const int kbase = kcol0 + kt * TM;
    f32x4 acc[4][4];
#pragma unroll
    for (int i = 0; i < 4; ++i)
#pragma unroll
      for (int j = 0; j < 4; ++j) { acc[i][j][0] = 0.f; acc[i][j][1] = 0.f; acc[i][j][2] = 0.f; acc[i][j][3] = 0.f; }
    float mn[4];
#pragma unroll
    for (int ni = 0; ni < 4; ++ni) mn[ni] = mnorm[kbase + wc * 64 + ni * 16 + lx];
    LOADREGS(0);
    WRITETILE(0);
    __syncthreads();
    for (int di = 0; di < NDT; ++di) {
      const int cur = di & 1;
      if (di + 1 < NDT) LOADREGS((di + 1) * BK2);
      {
        s16x8 ah[4], al[4], bh[4], bl[4];
#pragma unroll
        for (int i = 0; i < 4; ++i) {
          ah[i] = *(const s16x8*)&tiles[cur][0][(wr * 64 + i * 16 + lx) * BK2 + kg * 8];
          al[i] = *(const s16x8*)&tiles[cur][1][(wr * 64 + i * 16 + lx) * BK2 + kg * 8];
          bh[i] = *(const s16x8*)&tiles[cur][2][(wc * 64 + i * 16 + lx) * BK2 + kg * 8];
          bl[i] = *(const s16x8*)&tiles[cur][3][(wc * 64 + i * 16 + lx) * BK2 + kg * 8];
        }
#pragma unroll
        for (int i = 0; i < 4; ++i)
#pragma unroll
          for (int j = 0; j < 4; ++j) {
            acc[i][j] = __builtin_amdgcn_mfma_f32_16x16x32_bf16(ah[i], bh[j], acc[i][j], 0, 0, 0);
            acc[i][j] = __builtin_amdgcn_mfma_f32_16x16x32_bf16(ah[i], bl[j], acc[i][j], 0, 0, 0);
            acc[i][j] = __builtin_amdgcn_mfma_f32_16x16x32_bf16(al[i], bh[j], acc[i][j], 0, 0, 0);
          }
      }
      if (di + 1 < NDT) { WRITETILE(cur ^ 1); __syncthreads(); }
    }
#pragma unroll
    for (int mi = 0; mi < 4; ++mi)
#pragma unroll
      for (int r = 0; r < 4; ++r) {
        float v1 = FLT_MAX, v2 = FLT_MAX; int i1 = 0;
#pragma unroll
        for (int ni = 0; ni < 4; ++ni) {
          float v = mn[ni] - 2.f * acc[mi][ni][r];
          int k = kbase + wc * 64 + ni * 16 + lx;
          if (v < v1) { v2 = v1; v1 = v; i1 = k; } else { v2 = fminf(v2, v); }
        }
#pragma unroll
        for (int msk = 1; msk < 16; msk <<= 1) {
          float o1 = __shfl_xor(v1, msk);
          int   oi = __shfl_xor(i1, msk);
          float o2 = __shfl_xor(v2, msk);
          top2_merge(v1, i1, v2, o1, oi, o2);
        }
        if (lx == 0) {
          int row = wr * 64 + mi * 16 + kg * 4 + r;
          int s = row * 2 + wc;
          float a1 = sm1[s], a2 = sm2[s]; int ai = si1[s];
          top2_merge(a1, ai, a2, v1, i1, v2);
          sm1[s] = a1; sm2[s] = a2; si1[s] = ai;
        }
      }
  }
  __syncthreads();
  if (t < TM) {
    float a1 = sm1[t * 2], a2 = sm2[t * 2]; int ai = si1[t * 2];
    top2_merge(a1, ai, a2, sm1[t * 2 + 1], si1[t * 2 + 1], sm2[t * 2 + 1]);
    int n = srow0 + t;
    pval[n * SPLIT + split] = a1;
    pidx[n * SPLIT + split] = ai;
    pm2[n * SPLIT + split]  = a2;
  }
#undef LOADREGS
#undef WRITETILE
}

__global__ void merge_bins_kernel(const float* __restrict__ pval, const int* __restrict__ pidx,
                                  const float* __restrict__ pm2, const float* __restrict__ snorm,
                                  int* __restrict__ bins, float* __restrict__ inertia,
                                  int* __restrict__ flag_list, int* __restrict__ flag_count) {
  int n = blockIdx.x * 256 + threadIdx.x;
  float a1 = pval[n * SPLIT], a2 = pm2[n * SPLIT]; int ai = pidx[n * SPLIT];
  top2_merge(a1, ai, a2, pval[n * SPLIT + 1], pidx[n * SPLIT + 1], pm2[n * SPLIT + 1]);
  float r = 0.f;
  if (a2 - a1 <= MARGIN) {
    int idx = atomicAdd(flag_count, 1);
    flag_list[idx] = n;
  } else {
    bins[n] = ai;
    r = sqrtf(fmaxf(snorm[n] + a1, 0.f));
  }
  for (int off = 32; off; off >>= 1) r += __shfl_down(r, off);
  if ((threadIdx.x & 63) == 0) atomicAdd(inertia, r);
}

__global__ void scatter_kernel(const float* __restrict__ S, const int* __restrict__ bins,
                               float* __restrict__ csum, float* __restrict__ counts) {
  int w    = (blockIdx.x * 256 + threadIdx.x) >> 6;
  int lane = threadIdx.x & 63;
  if (w >= N_S) return;
  int b = bins[w];
  const float* src = S + (size_t)w * D_DIM;
  float* dst = csum + (size_t)b * D_DIM;
#pragma unroll
  for (int c = 0; c < D_DIM; c += 64) atomicAdd(dst + c + lane, src[c + lane]);
  if (lane == 0) atomicAdd(counts + b, 1.0f);
}

__global__ void finalize_kernel(const float* __restrict__ M, const float* __restrict__ W,
                                const float* __restrict__ counts, float* __restrict__ out) {
  int idx = blockIdx.x * 256 + threadIdx.x;
  int k = idx >> 9;
  float cnt = counts[k];
  float w   = W[k];
  float nw  = w + cnt;
  float alpha = 1.f / ((nw == 0.f) ? 1.f : nw);
  float m = M[idx];
  float v = (out[idx] + m * w) * alpha;
  out[idx] = (cnt == 0.f) ? m : v;
}

// ================================================================= launcher

extern "C" void kernel_launch(void* const* d_in, const int* in_sizes, int n_in,
                              void* d_out, int out_size, void* d_ws, size_t ws_size,
                              hipStream_t stream) {
  const float* S = (const float*)d_in[0];
  const float* M = (const float*)d_in[1];
  const float* W = (const float*)d_in[2];
  float* out = (float*)d_out;
  char* ws = (char*)d_ws;

  // fast-path workspace layout (bytes)
  const size_t oA  = 0;                                // A' 64 MiB
  const size_t oB  = oA  + (size_t)N_S * 1024 * 2;     // B' 4 MiB
  const size_t oPV = oB  + (size_t)K_C * 1024 * 2;     // pval 2 MiB
  const size_t oPM = oPV + (size_t)N_S * 16 * 4;
  const size_t oPI = oPM + (size_t)N_S * 16 * 4;
  const size_t oSN = oPI + (size_t)N_S * 16 * 4;       // snorm
  const size_t oMN = oSN + (size_t)N_S * 4;            // mnorm
  const size_t oBI = oMN + (size_t)K_C * 4;            // bins
  const size_t oCN = oBI + (size_t)N_S * 4;            // counts (int)
  const size_t oST = oCN + (size_t)K_C * 4;            // starts
  const size_t oCU = oST + (size_t)K_C * 4;            // cursor
  const size_t oBK = oCU + (size_t)K_C * 4;            // bucket
  const size_t oFC = oBK + (size_t)N_S * 4;            // flag_count
  const size_t oFL = oFC + 64;                         // flag_list
  const size_t NEED = oFL + (size_t)N_S * 4;

  if (ws_size >= NEED) {
    ushort* Aq = (ushort*)(ws + oA);
    ushort* Bq = (ushort*)(ws + oB);
    float* pval = (float*)(ws + oPV);
    float* pm2  = (float*)(ws + oPM);
    int*   pidx = (int*)(ws + oPI);
    float* snorm = (float*)(ws + oSN);
    float* mnorm = (float*)(ws + oMN);
    int* bins   = (int*)(ws + oBI);
    int* counts = (int*)(ws + oCN);
    int* starts = (int*)(ws + oST);
    int* cursor = (int*)(ws + oCU);
    int* bucket = (int*)(ws + oBK);
    int* flag_count = (int*)(ws + oFC);
    int* flag_list  = (int*)(ws + oFL);

    hipMemsetAsync(counts, 0, (size_t)K_C * 4, stream);
    hipMemsetAsync(flag_count, 0, 64, stream);
    hipMemsetAsync(out + KD, 0, sizeof(float), stream);

    preconvert_kernel<<<(N_S + K_C) / 4, 256, 0, stream>>>(S, M, Aq, Bq, snorm, mnorm);
    gemm_top2_kernel<<<4096, 256, 0, stream>>>(Aq, Bq, mnorm, pval, pidx, pm2);
    merge2_kernel<<<N_S / 256, 256, 0, stream>>>(pval, pidx, pm2, snorm, bins, out + KD,
                                                 counts, flag_list, flag_count);
    cleanup_kernel<true><<<512, 256, 0, stream>>>(S, M, snorm, mnorm, flag_list, flag_count,
                                                  bins, out + KD, counts);
    prefix_kernel<<<1, 256, 0, stream>>>(counts, starts, cursor);
    fill_kernel<<<N_S / 256, 256, 0, stream>>>(bins, cursor, bucket);
    gather_finalize_kernel<<<K_C, 256, 0, stream>>>(S, M, W, starts, counts, bucket, out);
  } else {
    float* mnorm     = (float*)ws;
    float* snorm     = mnorm + K_C;
    int*   bins      = (int*)(snorm + N_S);
    float* counts    = (float*)(bins + N_S);
    float* pval      = counts + K_C;
    int*   pidx      = (int*)(pval + (size_t)N_S * 2);
    float* pm2       = (float*)(pidx + (size_t)N_S * 2);
    int*   flag_count= (int*)(pm2 + (size_t)N_S * 2);
    int*   flag_list = flag_count + 16;

    hipMemsetAsync(d_out, 0, (size_t)(KD + 1) * sizeof(float), stream);
    hipMemsetAsync(counts, 0, K_C * sizeof(float), stream);
    hipMemsetAsync(flag_count, 0, sizeof(int), stream);

    row_norms_kernel<<<(N_S + K_C) / 4, 256, 0, stream>>>(S, M, snorm, mnorm);
    dist_argmin_kernel<<<(N_S / TM) * SPLIT, 256, 0, stream>>>(S, M, mnorm, pval, pidx, pm2);
    merge_bins_kernel<<<N_S / 256, 256, 0, stream>>>(pval, pidx, pm2, snorm, bins, out + KD,
                                                     flag_list, flag_count);
    cleanup_kernel<false><<<1024, 256, 0, stream>>>(S, M, snorm, mnorm, flag_list, flag_count,
                                                    bins, out + KD, (int*)nullptr);
    scatter_kernel<<<N_S / 4, 256, 0, stream>>>(S, bins, out, counts);
    finalize_kernel<<<KD / 256, 256, 0, stream>>>(M, W, counts, out);
  }
}

// Round 4
// 597.317 us; speedup vs baseline: 1.6647x; 1.1731x over previous
//
#include <hip/hip_runtime.h>
#include <hip/hip_bf16.h>
#include <math.h>
#include <float.h>

#define N_S   32768
#define K_C   2048
#define D_DIM 512
#define KD    (K_C * D_DIM)
#define MARGIN 0.02f

using s16x8 = __attribute__((ext_vector_type(8))) short;
using f32x4 = __attribute__((ext_vector_type(4))) float;

typedef const __attribute__((address_space(1))) unsigned int glb_u32_t;
typedef __attribute__((address_space(3))) unsigned int lds_u32_t;

__device__ __forceinline__ void gll16(const void* g, void* l) {
  __builtin_amdgcn_global_load_lds((glb_u32_t*)g, (lds_u32_t*)l, 16, 0, 0);
}

__device__ inline void cvt_hl(float x, ushort& hb, ushort& lb) {
  __hip_bfloat16 h = __float2bfloat16(x);
  hb = *reinterpret_cast<ushort*>(&h);
  float hf = __bfloat162float(h);
  __hip_bfloat16 l = __float2bfloat16(x - hf);
  lb = *reinterpret_cast<ushort*>(&l);
}

__device__ inline void top2_merge(float& a1, int& ai, float& a2, float b1, int bi, float b2) {
  if (b1 < a1 || (b1 == a1 && bi < ai)) { a2 = fminf(a1, b2); a1 = b1; ai = bi; }
  else { a2 = fminf(a2, b1); }
}

// ================================================================ FAST PATH

// Convert fp32 -> (hi, lo) bf16, pre-tiled+swizzled for the GEMM; fused row norms.
__global__ void preconvert_kernel(const float* __restrict__ S, const float* __restrict__ M,
                                  ushort* __restrict__ Aq, ushort* __restrict__ Bq,
                                  float* __restrict__ snorm, float* __restrict__ mnorm) {
  int row = blockIdx.x * 4 + (threadIdx.x >> 6);
  int l   = threadIdx.x & 63;
  bool isS = row < N_S;
  int lr = isS ? row : row - N_S;
  const float* src = (isS ? S : M) + (size_t)lr * D_DIM + l * 8;
  float4 u0 = *(const float4*)(src);
  float4 u1 = *(const float4*)(src + 4);
  float x[8] = {u0.x, u0.y, u0.z, u0.w, u1.x, u1.y, u1.z, u1.w};
  s16x8 hv, lv;
  float nrm = 0.f;
#pragma unroll
  for (int i = 0; i < 8; ++i) {
    nrm += x[i] * x[i];
    ushort hb, lb;
    cvt_hl(x[i], hb, lb);
    hv[i] = (short)hb; lv[i] = (short)lb;
  }
  int r = lr & 127, tile = lr >> 7;
  int kc = l >> 3, slot = (l & 7) ^ (r & 7);
  ushort* dst = isS ? Aq : Bq;
  size_t basehi = ((size_t)(tile * 16 + kc)     * 128 + r) * 64 + slot * 8;
  size_t baselo = ((size_t)(tile * 16 + 8 + kc) * 128 + r) * 64 + slot * 8;
  *(s16x8*)(dst + basehi) = hv;
  *(s16x8*)(dst + baselo) = lv;
  for (int off = 32; off; off >>= 1) nrm += __shfl_down(nrm, off);
  if (l == 0) { if (isS) snorm[lr] = nrm; else mnorm[lr] = nrm; }
}

// 128x128 tile bf16-split GEMM (-2*S.M part) + fused per-row top-2 partials.
__launch_bounds__(256, 3)
__global__ void gemm_top2_kernel(const ushort* __restrict__ Aq, const ushort* __restrict__ Bq,
                                 const float* __restrict__ mnorm,
                                 float* __restrict__ pval, int* __restrict__ pidx,
                                 float* __restrict__ pm2) {
  __shared__ __align__(16) ushort lA[128 * 64];
  __shared__ __align__(16) ushort lB[128 * 64];
  __shared__ float rv1[128 * 2], rv2[128 * 2];
  __shared__ int   ri1[128 * 2];
  const int t = threadIdx.x, lane = t & 63, wid = t >> 6;
  const int wr = wid >> 1, wc = wid & 1;
  const int lx = lane & 15, kg = lane >> 4;
  int bid = ((int)blockIdx.x & 7) * 512 + ((int)blockIdx.x >> 3);
  const int rt = bid >> 4, ct = bid & 15;

  f32x4 acc[4][4];
#pragma unroll
  for (int i = 0; i < 4; ++i)
#pragma unroll
    for (int j = 0; j < 4; ++j) { acc[i][j][0] = 0.f; acc[i][j][1] = 0.f; acc[i][j][2] = 0.f; acc[i][j][3] = 0.f; }

  for (int s = 0; s < 24; ++s) {
    int akc = (s < 16) ? (s & 7) : (s - 8);
    int bkc = s & 15;
    const char* ga = (const char*)(Aq + ((size_t)(rt * 16 + akc) << 13));
    const char* gb = (const char*)(Bq + ((size_t)(ct * 16 + bkc) << 13));
    __syncthreads();
#pragma unroll
    for (int q = 0; q < 4; ++q) {
      gll16(ga + wid * 1024 + lane * 16 + q * 4096, (char*)lA + wid * 1024 + q * 4096);
      gll16(gb + wid * 1024 + lane * 16 + q * 4096, (char*)lB + wid * 1024 + q * 4096);
    }
    __syncthreads();
#pragma unroll
    for (int kk = 0; kk < 2; ++kk) {
      s16x8 af[4], bf[4];
#pragma unroll
      for (int i = 0; i < 4; ++i) {
        int r = wr * 64 + i * 16 + lx;
        af[i] = *(const s16x8*)&lA[r * 64 + (((kk * 4 + kg) ^ (lx & 7)) * 8)];
      }
#pragma unroll
      for (int j = 0; j < 4; ++j) {
        int r = wc * 64 + j * 16 + lx;
        bf[j] = *(const s16x8*)&lB[r * 64 + (((kk * 4 + kg) ^ (lx & 7)) * 8)];
      }
#pragma unroll
      for (int i = 0; i < 4; ++i)
#pragma unroll
        for (int j = 0; j < 4; ++j)
          acc[i][j] = __builtin_amdgcn_mfma_f32_16x16x32_bf16(af[i], bf[j], acc[i][j], 0, 0, 0);
    }
  }

  float mn[4];
#pragma unroll
  for (int j = 0; j < 4; ++j) mn[j] = mnorm[ct * 128 + wc * 64 + j * 16 + lx];
#pragma unroll
  for (int i = 0; i < 4; ++i)
#pragma unroll
    for (int reg = 0; reg < 4; ++reg) {
      float v1 = FLT_MAX, v2 = FLT_MAX; int i1 = 0;
#pragma unroll
      for (int j = 0; j < 4; ++j) {
        float v = mn[j] - 2.f * acc[i][j][reg];
        int k = ct * 128 + wc * 64 + j * 16 + lx;
        if (v < v1) { v2 = v1; v1 = v; i1 = k; } else v2 = fminf(v2, v);
      }
#pragma unroll
      for (int msk = 1; msk < 16; msk <<= 1) {
        float o1 = __shfl_xor(v1, msk);
        int   oi = __shfl_xor(i1, msk);
        float o2 = __shfl_xor(v2, msk);
        top2_merge(v1, i1, v2, o1, oi, o2);
      }
      if (lx == 0) {
        int rowr = wr * 64 + i * 16 + kg * 4 + reg;
        rv1[rowr * 2 + wc] = v1; ri1[rowr * 2 + wc] = i1; rv2[rowr * 2 + wc] = v2;
      }
    }
  __syncthreads();
  if (t < 128) {
    float a1 = rv1[t * 2], a2 = rv2[t * 2]; int ai = ri1[t * 2];
    top2_merge(a1, ai, a2, rv1[t * 2 + 1], ri1[t * 2 + 1], rv2[t * 2 + 1]);
    size_t n = (size_t)rt * 128 + t;
    pval[n * 16 + ct] = a1;
    pidx[n * 16 + ct] = ai;
    pm2 [n * 16 + ct] = a2;
  }
}

// merge 16 col-tile partials per row; flag ambiguous; count + inertia for sure rows
__global__ void merge2_kernel(const float* __restrict__ pval, const int* __restrict__ pidx,
                              const float* __restrict__ pm2, const float* __restrict__ snorm,
                              int* __restrict__ bins, float* __restrict__ inertia,
                              int* __restrict__ counts,
                              int* __restrict__ flag_list, int* __restrict__ flag_count) {
  int n = blockIdx.x * 256 + threadIdx.x;
  float a1 = FLT_MAX, a2 = FLT_MAX; int ai = 0x7fffffff;
  for (int c = 0; c < 16; ++c)
    top2_merge(a1, ai, a2, pval[(size_t)n * 16 + c], pidx[(size_t)n * 16 + c], pm2[(size_t)n * 16 + c]);
  float r = 0.f;
  if (a2 - a1 <= MARGIN) {
    int idx = atomicAdd(flag_count, 1);
    flag_list[idx] = n;
  } else {
    bins[n] = ai;
    atomicAdd(&counts[ai], 1);
    r = sqrtf(fmaxf(snorm[n] + a1, 0.f));
  }
  for (int off = 32; off; off >>= 1) r += __shfl_down(r, off);
  if ((threadIdx.x & 63) == 0) atomicAdd(inertia, r);
}

// exact fp32 re-resolve for flagged samples — cluster-parallel version.
// One block per flagged sample; thread t owns clusters {c*256+t}, d-loop outer,
// 8 independent accumulator chains (ILP), then (val,idx) min-reduce.
template <bool ADDCOUNT>
__launch_bounds__(256)
__global__ void cleanup_kernel(const float* __restrict__ S, const float* __restrict__ M,
                               const float* __restrict__ snorm, const float* __restrict__ mnorm,
                               const int* __restrict__ flag_list, const int* __restrict__ flag_count,
                               int* __restrict__ bins, float* __restrict__ inertia,
                               int* __restrict__ counts) {
  __shared__ __align__(16) float sS[D_DIM];
  __shared__ float wv[4];
  __shared__ int   wk[4];
  const int t = threadIdx.x, lane = t & 63, wid = t >> 6;
  const int cnt = *flag_count;
  for (int fi = blockIdx.x; fi < cnt; fi += gridDim.x) {
    int n = flag_list[fi];
    __syncthreads();   // protect sS reuse across grid-stride iterations
    for (int i = t; i < D_DIM / 4; i += 256)
      ((float4*)sS)[i] = ((const float4*)(S + (size_t)n * D_DIM))[i];
    __syncthreads();

    float acc[8];
    const float4* mr[8];
#pragma unroll
    for (int c = 0; c < 8; ++c) {
      acc[c] = 0.f;
      mr[c] = (const float4*)(M + (size_t)(c * 256 + t) * D_DIM);
    }
    for (int d = 0; d < D_DIM / 4; ++d) {
      float4 s4 = ((const float4*)sS)[d];
#pragma unroll
      for (int c = 0; c < 8; ++c) {
        float4 m4 = mr[c][d];
        acc[c] += m4.x * s4.x + m4.y * s4.y + m4.z * s4.z + m4.w * s4.w;
      }
    }
    float best = FLT_MAX; int bk = 0;
#pragma unroll
    for (int c = 0; c < 8; ++c) {           // c ascending => k ascending per thread
      int k = c * 256 + t;
      float dist = mnorm[k] - 2.f * acc[c];
      if (dist < best) { best = dist; bk = k; }
    }
    // wave min-reduce with lowest-index tie-break
#pragma unroll
    for (int off = 1; off < 64; off <<= 1) {
      float ob = __shfl_xor(best, off);
      int   ok = __shfl_xor(bk, off);
      if (ob < best || (ob == best && ok < bk)) { best = ob; bk = ok; }
    }
    if (lane == 0) { wv[wid] = best; wk[wid] = bk; }
    __syncthreads();
    if (t == 0) {
      float b = wv[0]; int bi = wk[0];
      for (int w = 1; w < 4; ++w)
        if (wv[w] < b || (wv[w] == b && wk[w] < bi)) { b = wv[w]; bi = wk[w]; }
      bins[n] = bi;
      if (ADDCOUNT) atomicAdd(&counts[bi], 1);
      atomicAdd(inertia, sqrtf(fmaxf(snorm[n] + b, 0.f)));
    }
  }
}

// exclusive prefix sum over 2048 counts (single block)
__global__ void prefix_kernel(const int* __restrict__ counts, int* __restrict__ starts,
                              int* __restrict__ cursor) {
  __shared__ int part[256];
  int t = threadIdx.x;
  int loc[8]; int s = 0;
#pragma unroll
  for (int i = 0; i < 8; ++i) { loc[i] = s; s += counts[t * 8 + i]; }
  part[t] = s;
  __syncthreads();
  for (int off = 1; off < 256; off <<= 1) {
    int v = (t >= off) ? part[t - off] : 0;
    __syncthreads();
    part[t] += v;
    __syncthreads();
  }
  int base = (t == 0) ? 0 : part[t - 1];
#pragma unroll
  for (int i = 0; i < 8; ++i) { starts[t * 8 + i] = base + loc[i]; cursor[t * 8 + i] = base + loc[i]; }
}

__global__ void fill_kernel(const int* __restrict__ bins, int* __restrict__ cursor,
                            int* __restrict__ bucket) {
  int n = blockIdx.x * 256 + threadIdx.x;
  int pos = atomicAdd(&cursor[bins[n]], 1);
  bucket[pos] = n;
}

// per-cluster gather of assigned samples + finalize new_means (no atomics)
__global__ void gather_finalize_kernel(const float* __restrict__ S, const float* __restrict__ M,
                                       const float* __restrict__ W,
                                       const int* __restrict__ starts, const int* __restrict__ counts,
                                       const int* __restrict__ bucket, float* __restrict__ out) {
  int k = blockIdx.x, t = threadIdx.x;
  int cnt = counts[k], s0 = starts[k];
  float acc0 = 0.f, acc1 = 0.f;
  for (int i = 0; i < cnt; ++i) {
    const float* row = S + (size_t)bucket[s0 + i] * D_DIM;
    acc0 += row[t];
    acc1 += row[t + 256];
  }
  float w = W[k];
  float nw = w + (float)cnt;
  float alpha = 1.f / ((nw == 0.f) ? 1.f : nw);
  size_t o = (size_t)k * D_DIM + t;
  float m0 = M[o], m1 = M[o + 256];
  out[o]       = (cnt == 0) ? m0 : (acc0 + m0 * w) * alpha;
  out[o + 256] = (cnt == 0) ? m1 : (acc1 + m1 * w) * alpha;
}

// ============================================================ FALLBACK PATH

#define TM    128
#define BK2   32
#define SPLIT 2
#define KPER  (K_C / SPLIT)
#define NKT   (KPER / TM)
#define NDT   (D_DIM / BK2)

__global__ void row_norms_kernel(const float* __restrict__ S, const float* __restrict__ M,
                                 float* __restrict__ snorm, float* __restrict__ mnorm) {
  int row  = blockIdx.x * 4 + (threadIdx.x >> 6);
  int lane = threadIdx.x & 63;
  if (row >= N_S + K_C) return;
  const float* src;
  float* dst;
  if (row < N_S) { src = S + (size_t)row * D_DIM; dst = snorm + row; }
  else { int r = row - N_S; src = M + (size_t)r * D_DIM; dst = mnorm + r; }
  float4 v0 = *(const float4*)(src + lane * 4);
  float4 v1 = *(const float4*)(src + 256 + lane * 4);
  float s = v0.x*v0.x + v0.y*v0.y + v0.z*v0.z + v0.w*v0.w
          + v1.x*v1.x + v1.y*v1.y + v1.z*v1.z + v1.w*v1.w;
  for (int off = 32; off; off >>= 1) s += __shfl_down(s, off);
  if (lane == 0) *dst = s;
}

__launch_bounds__(256)
__global__ void dist_argmin_kernel(const float* __restrict__ S, const float* __restrict__ M,
                                   const float* __restrict__ mnorm,
                                   float* __restrict__ pval, int* __restrict__ pidx,
                                   float* __restrict__ pm2) {
  __shared__ ushort tiles[2][4][TM * BK2];
  __shared__ float sm1[TM * 2];
  __shared__ float sm2[TM * 2];
  __shared__ int   si1[TM * 2];
  const int t    = threadIdx.x;
  const int lane = t & 63, wid = t >> 6;
  const int wr   = wid >> 1, wc = wid & 1;
  const int lx   = lane & 15, kg = lane >> 4;
  const int stile = blockIdx.x >> 1, split = blockIdx.x & 1;
  const int srow0 = stile * TM;
  const int kcol0 = split * KPER;
  for (int i = t; i < TM * 2; i += 256) { sm1[i] = FLT_MAX; sm2[i] = FLT_MAX; si1[i] = 0; }
  float4 av[4], bv[4];
#define LOADREGS(dtoff) do { \
    const float* Ag = S + (size_t)srow0 * D_DIM + (dtoff); \
    const float* Bg = M + (size_t)kbase * D_DIM + (dtoff); \
    _Pragma("unroll") \
    for (int q = 0; q < 4; ++q) { \
      int id = t + q * 256; int r_ = id >> 3, c_ = (id & 7) * 4; \
      av[q] = *(const float4*)(Ag + (size_t)r_ * D_DIM + c_); \
      bv[q] = *(const float4*)(Bg + (size_t)r_ * D_DIM + c_); \
    } } while (0)
#define WRITETILE(buf) do { \
    _Pragma("unroll") \
    for (int q = 0; q < 4; ++q) { \
      int id = t + q * 256; int r_ = id >> 3, c_ = (id & 7) * 4; \
      ushort4 h4, l4; \
      cvt_hl(av[q].x, h4.x, l4.x); cvt_hl(av[q].y, h4.y, l4.y); \
      cvt_hl(av[q].z, h4.z, l4.z); cvt_hl(av[q].w, h4.w, l4.w); \
      *(ushort4*)&tiles[buf][0][r_ * BK2 + c_] = h4; \
      *(ushort4*)&tiles[buf][1][r_ * BK2 + c_] = l4; \
      cvt_hl(bv[q].x, h4.x, l4.x); cvt_hl(bv[q].y, h4.y, l4.y); \
      cvt_hl(bv[q].z, h4.z, l4.z); cvt_hl(bv[q].w, h4.w, l4.w); \
      *(ushort4*)&tiles[buf][2][r_ * BK2 + c_] = h4; \
      *(ushort4*)&tiles[buf][3][r_ * BK2 + c_] = l4; \
    } } while (0)
  for (int kt = 0; kt < NKT; ++kt) {
    const int kbase = kcol0 + kt * TM;
    f32x4 acc[4][4];
#pragma unroll
    for (int i = 0; i < 4; ++i)
#pragma unroll
      for (int j = 0; j < 4; ++j) { acc[i][j][0] = 0.f; acc[i][j][1] = 0.f; acc[i][j][2] = 0.f; acc[i][j][3] = 0.f; }
    float mn[4];
#pragma unroll
    for (int ni = 0; ni < 4; ++ni) mn[ni] = mnorm[kbase + wc * 64 + ni * 16 + lx];
    LOADREGS(0);
    WRITETILE(0);
    __syncthreads();
    for (int di = 0; di < NDT; ++di) {
      const int cur = di & 1;
      if (di + 1 < NDT) LOADREGS((di + 1) * BK2);
      {
        s16x8 ah[4], al[4], bh[4], bl[4];
#pragma unroll
        for (int i = 0; i < 4; ++i) {
          ah[i] = *(const s16x8*)&tiles[cur][0][(wr * 64 + i * 16 + lx) * BK2 + kg * 8];
          al[i] = *(const s16x8*)&tiles[cur][1][(wr * 64 + i * 16 + lx) * BK2 + kg * 8];
          bh[i] = *(const s16x8*)&tiles[cur][2][(wc * 64 + i * 16 + lx) * BK2 + kg * 8];
          bl[i] = *(const s16x8*)&tiles[cur][3][(wc * 64 + i * 16 + lx) * BK2 + kg * 8];
        }
#pragma unroll
        for (int i = 0; i < 4; ++i)
#pragma unroll
          for (int j = 0; j < 4; ++j) {
            acc[i][j] = __builtin_amdgcn_mfma_f32_16x16x32_bf16(ah[i], bh[j], acc[i][j], 0, 0, 0);
            acc[i][j] = __builtin_amdgcn_mfma_f32_16x16x32_bf16(ah[i], bl[j], acc[i][j], 0, 0, 0);
            acc[i][j] = __builtin_amdgcn_mfma_f32_16x16x32_bf16(al[i], bh[j], acc[i][j], 0, 0, 0);
          }
      }
      if (di + 1 < NDT) { WRITETILE(cur ^ 1); __syncthreads(); }
    }
#pragma unroll
    for (int mi = 0; mi < 4; ++mi)
#pragma unroll
      for (int r = 0; r < 4; ++r) {
        float v1 = FLT_MAX, v2 = FLT_MAX; int i1 = 0;
#pragma unroll
        for (int ni = 0; ni < 4; ++ni) {
          float v = mn[ni] - 2.f * acc[mi][ni][r];
          int k = kbase + wc * 64 + ni * 16 + lx;
          if (v < v1) { v2 = v1; v1 = v; i1 = k; } else { v2 = fminf(v2, v); }
        }
#pragma unroll
        for (int msk = 1; msk < 16; msk <<= 1) {
          float o1 = __shfl_xor(v1, msk);
          int   oi = __shfl_xor(i1, msk);
          float o2 = __shfl_xor(v2, msk);
          top2_merge(v1, i1, v2, o1, oi, o2);
        }
        if (lx == 0) {
          int row = wr * 64 + mi * 16 + kg * 4 + r;
          int s = row * 2 + wc;
          float a1 = sm1[s], a2 = sm2[s]; int ai = si1[s];
          top2_merge(a1, ai, a2, v1, i1, v2);
          sm1[s] = a1; sm2[s] = a2; si1[s] = ai;
        }
      }
  }
  __syncthreads();
  if (t < TM) {
    float a1 = sm1[t * 2], a2 = sm2[t * 2]; int ai = si1[t * 2];
    top2_merge(a1, ai, a2, sm1[t * 2 + 1], si1[t * 2 + 1], sm2[t * 2 + 1]);
    int n = srow0 + t;
    pval[n * SPLIT + split] = a1;
    pidx[n * SPLIT + split] = ai;
    pm2[n * SPLIT + split]  = a2;
  }
#undef LOADREGS
#undef WRITETILE
}

__global__ void merge_bins_kernel(const float* __restrict__ pval, const int* __restrict__ pidx,
                                  const float* __restrict__ pm2, const float* __restrict__ snorm,
                                  int* __restrict__ bins, float* __restrict__ inertia,
                                  int* __restrict__ flag_list, int* __restrict__ flag_count) {
  int n = blockIdx.x * 256 + threadIdx.x;
  float a1 = pval[n * SPLIT], a2 = pm2[n * SPLIT]; int ai = pidx[n * SPLIT];
  top2_merge(a1, ai, a2, pval[n * SPLIT + 1], pidx[n * SPLIT + 1], pm2[n * SPLIT + 1]);
  float r = 0.f;
  if (a2 - a1 <= MARGIN) {
    int idx = atomicAdd(flag_count, 1);
    flag_list[idx] = n;
  } else {
    bins[n] = ai;
    r = sqrtf(fmaxf(snorm[n] + a1, 0.f));
  }
  for (int off = 32; off; off >>= 1) r += __shfl_down(r, off);
  if ((threadIdx.x & 63) == 0) atomicAdd(inertia, r);
}

__global__ void scatter_kernel(const float* __restrict__ S, const int* __restrict__ bins,
                               float* __restrict__ csum, float* __restrict__ counts) {
  int w    = (blockIdx.x * 256 + threadIdx.x) >> 6;
  int lane = threadIdx.x & 63;
  if (w >= N_S) return;
  int b = bins[w];
  const float* src = S + (size_t)w * D_DIM;
  float* dst = csum + (size_t)b * D_DIM;
#pragma unroll
  for (int c = 0; c < D_DIM; c += 64) atomicAdd(dst + c + lane, src[c + lane]);
  if (lane == 0) atomicAdd(counts + b, 1.0f);
}

__global__ void finalize_kernel(const float* __restrict__ M, const float* __restrict__ W,
                                const float* __restrict__ counts, float* __restrict__ out) {
  int idx = blockIdx.x * 256 + threadIdx.x;
  int k = idx >> 9;
  float cnt = counts[k];
  float w   = W[k];
  float nw  = w + cnt;
  float alpha = 1.f / ((nw == 0.f) ? 1.f : nw);
  float m = M[idx];
  float v = (out[idx] + m * w) * alpha;
  out[idx] = (cnt == 0.f) ? m : v;
}

// ================================================================= launcher

extern "C" void kernel_launch(void* const* d_in, const int* in_sizes, int n_in,
                              void* d_out, int out_size, void* d_ws, size_t ws_size,
                              hipStream_t stream) {
  const float* S = (const float*)d_in[0];
  const float* M = (const float*)d_in[1];
  const float* W = (const float*)d_in[2];
  float* out = (float*)d_out;
  char* ws = (char*)d_ws;

  const size_t oA  = 0;
  const size_t oB  = oA  + (size_t)N_S * 1024 * 2;
  const size_t oPV = oB  + (size_t)K_C * 1024 * 2;
  const size_t oPM = oPV + (size_t)N_S * 16 * 4;
  const size_t oPI = oPM + (size_t)N_S * 16 * 4;
  const size_t oSN = oPI + (size_t)N_S * 16 * 4;
  const size_t oMN = oSN + (size_t)N_S * 4;
  const size_t oBI = oMN + (size_t)K_C * 4;
  const size_t oCN = oBI + (size_t)N_S * 4;
  const size_t oST = oCN + (size_t)K_C * 4;
  const size_t oCU = oST + (size_t)K_C * 4;
  const size_t oBK = oCU + (size_t)K_C * 4;
  const size_t oFC = oBK + (size_t)N_S * 4;
  const size_t oFL = oFC + 64;
  const size_t NEED = oFL + (size_t)N_S * 4;

  if (ws_size >= NEED) {
    ushort* Aq = (ushort*)(ws + oA);
    ushort* Bq = (ushort*)(ws + oB);
    float* pval = (float*)(ws + oPV);
    float* pm2  = (float*)(ws + oPM);
    int*   pidx = (int*)(ws + oPI);
    float* snorm = (float*)(ws + oSN);
    float* mnorm = (float*)(ws + oMN);
    int* bins   = (int*)(ws + oBI);
    int* counts = (int*)(ws + oCN);
    int* starts = (int*)(ws + oST);
    int* cursor = (int*)(ws + oCU);
    int* bucket = (int*)(ws + oBK);
    int* flag_count = (int*)(ws + oFC);
    int* flag_list  = (int*)(ws + oFL);

    hipMemsetAsync(counts, 0, (size_t)K_C * 4, stream);
    hipMemsetAsync(flag_count, 0, 64, stream);
    hipMemsetAsync(out + KD, 0, sizeof(float), stream);

    preconvert_kernel<<<(N_S + K_C) / 4, 256, 0, stream>>>(S, M, Aq, Bq, snorm, mnorm);
    gemm_top2_kernel<<<4096, 256, 0, stream>>>(Aq, Bq, mnorm, pval, pidx, pm2);
    merge2_kernel<<<N_S / 256, 256, 0, stream>>>(pval, pidx, pm2, snorm, bins, out + KD,
                                                 counts, flag_list, flag_count);
    cleanup_kernel<true><<<2048, 256, 0, stream>>>(S, M, snorm, mnorm, flag_list, flag_count,
                                                   bins, out + KD, counts);
    prefix_kernel<<<1, 256, 0, stream>>>(counts, starts, cursor);
    fill_kernel<<<N_S / 256, 256, 0, stream>>>(bins, cursor, bucket);
    gather_finalize_kernel<<<K_C, 256, 0, stream>>>(S, M, W, starts, counts, bucket, out);
  } else {
    float* mnorm     = (float*)ws;
    float* snorm     = mnorm + K_C;
    int*   bins      = (int*)(snorm + N_S);
    float* counts    = (float*)(bins + N_S);
    float* pval      = counts + K_C;
    int*   pidx      = (int*)(pval + (size_t)N_S * 2);
    float* pm2       = (float*)(pidx + (size_t)N_S * 2);
    int*   flag_count= (int*)(pm2 + (size_t)N_S * 2);
    int*   flag_list = flag_count + 16;

    hipMemsetAsync(d_out, 0, (size_t)(KD + 1) * sizeof(float), stream);
    hipMemsetAsync(counts, 0, K_C * sizeof(float), stream);
    hipMemsetAsync(flag_count, 0, sizeof(int), stream);

    row_norms_kernel<<<(N_S + K_C) / 4, 256, 0, stream>>>(S, M, snorm, mnorm);
    dist_argmin_kernel<<<(N_S / TM) * SPLIT, 256, 0, stream>>>(S, M, mnorm, pval, pidx, pm2);
    merge_bins_kernel<<<N_S / 256, 256, 0, stream>>>(pval, pidx, pm2, snorm, bins, out + KD,
                                                     flag_list, flag_count);
    cleanup_kernel<false><<<1024, 256, 0, stream>>>(S, M, snorm, mnorm, flag_list, flag_count,
                                                    bins, out + KD, (int*)nullptr);
    scatter_kernel<<<N_S / 4, 256, 0, stream>>>(S, bins, out, counts);
    finalize_kernel<<<KD / 256, 256, 0, stream>>>(M, W, counts, out);
  }
}

// Round 5
// 501.778 us; speedup vs baseline: 1.9817x; 1.1904x over previous
//
#include <hip/hip_runtime.h>
#include <hip/hip_bf16.h>
#include <math.h>
#include <float.h>

#define N_S   32768
#define K_C   2048
#define D_DIM 512
#define KD    (K_C * D_DIM)
#define MARGIN 0.02f

using s16x8 = __attribute__((ext_vector_type(8))) short;
using f32x4 = __attribute__((ext_vector_type(4))) float;

typedef const __attribute__((address_space(1))) unsigned int glb_u32_t;
typedef __attribute__((address_space(3))) unsigned int lds_u32_t;

__device__ __forceinline__ void gll16(const void* g, void* l) {
  __builtin_amdgcn_global_load_lds((glb_u32_t*)g, (lds_u32_t*)l, 16, 0, 0);
}

__device__ inline void cvt_hl(float x, ushort& hb, ushort& lb) {
  __hip_bfloat16 h = __float2bfloat16(x);
  hb = *reinterpret_cast<ushort*>(&h);
  float hf = __bfloat162float(h);
  __hip_bfloat16 l = __float2bfloat16(x - hf);
  lb = *reinterpret_cast<ushort*>(&l);
}

__device__ inline void top2_merge(float& a1, int& ai, float& a2, float b1, int bi, float b2) {
  if (b1 < a1 || (b1 == a1 && bi < ai)) { a2 = fminf(a1, b2); a1 = b1; ai = bi; }
  else { a2 = fminf(a2, b1); }
}

// ================================================================ FAST PATH

// Convert fp32 -> (hi, lo) bf16, pre-tiled+swizzled; fused row norms.
// Layout: blocks of [128 rows][64 bf16], block id = tile(=row/128)*16 + kc
// (kc 0..7 hi d-chunks, 8..15 lo). 16B chunk c of row r stored at slot c^(r&7).
__global__ void preconvert_kernel(const float* __restrict__ S, const float* __restrict__ M,
                                  ushort* __restrict__ Aq, ushort* __restrict__ Bq,
                                  float* __restrict__ snorm, float* __restrict__ mnorm) {
  int row = blockIdx.x * 4 + (threadIdx.x >> 6);
  int l   = threadIdx.x & 63;
  bool isS = row < N_S;
  int lr = isS ? row : row - N_S;
  const float* src = (isS ? S : M) + (size_t)lr * D_DIM + l * 8;
  float4 u0 = *(const float4*)(src);
  float4 u1 = *(const float4*)(src + 4);
  float x[8] = {u0.x, u0.y, u0.z, u0.w, u1.x, u1.y, u1.z, u1.w};
  s16x8 hv, lv;
  float nrm = 0.f;
#pragma unroll
  for (int i = 0; i < 8; ++i) {
    nrm += x[i] * x[i];
    ushort hb, lb;
    cvt_hl(x[i], hb, lb);
    hv[i] = (short)hb; lv[i] = (short)lb;
  }
  int r = lr & 127, tile = lr >> 7;
  int kc = l >> 3, slot = (l & 7) ^ (r & 7);
  ushort* dst = isS ? Aq : Bq;
  size_t basehi = ((size_t)(tile * 16 + kc)     * 128 + r) * 64 + slot * 8;
  size_t baselo = ((size_t)(tile * 16 + 8 + kc) * 128 + r) * 64 + slot * 8;
  *(s16x8*)(dst + basehi) = hv;
  *(s16x8*)(dst + baselo) = lv;
  for (int off = 32; off; off >>= 1) nrm += __shfl_down(nrm, off);
  if (l == 0) { if (isS) snorm[lr] = nrm; else mnorm[lr] = nrm; }
}

// ---------- 256x256-tile, 8-wave, 4-phase-per-K-tile split-bf16 GEMM + top-2 ----------
#define STAGE_A(buf, akc) do { \
  const ushort* sA0_ = Aq + (((size_t)(2*rt+0)*16 + (size_t)(akc)) << 13); \
  const ushort* sA1_ = Aq + (((size_t)(2*rt+1)*16 + (size_t)(akc)) << 13); \
  ushort* dA_ = &lds[(buf)*32768]; \
  gll16(sA0_ + t*8,        dA_ + t*8); \
  gll16(sA0_ + 4096 + t*8, dA_ + 4096 + t*8); \
  gll16(sA1_ + t*8,        dA_ + 8192 + t*8); \
  gll16(sA1_ + 4096 + t*8, dA_ + 12288 + t*8); \
} while (0)

#define STAGE_B(buf, bkc) do { \
  const ushort* sB0_ = Bq + (((size_t)(2*ct+0)*16 + (size_t)(bkc)) << 13); \
  const ushort* sB1_ = Bq + (((size_t)(2*ct+1)*16 + (size_t)(bkc)) << 13); \
  ushort* dB_ = &lds[(buf)*32768 + 16384]; \
  gll16(sB0_ + t*8,        dB_ + t*8); \
  gll16(sB0_ + 4096 + t*8, dB_ + 4096 + t*8); \
  gll16(sB1_ + t*8,        dB_ + 8192 + t*8); \
  gll16(sB1_ + 4096 + t*8, dB_ + 12288 + t*8); \
} while (0)

#define READ_A(buf, ib, kk, dst) do { \
  const ushort* bA_ = &lds[(buf)*32768 + wr*8192]; \
  _Pragma("unroll") \
  for (int i_ = 0; i_ < 4; ++i_) \
    dst[i_] = *(const s16x8*)&bA_[(((ib)*64 + i_*16 + lx)*64) + ((((kk)*4+kg) ^ (lx&7))*8)]; \
} while (0)

#define READ_B(buf, kk, dst) do { \
  const ushort* bB_ = &lds[(buf)*32768 + 16384 + (wc>>1)*8192 + (wc&1)*4096]; \
  _Pragma("unroll") \
  for (int j_ = 0; j_ < 4; ++j_) \
    dst[j_] = *(const s16x8*)&bB_[((j_*16 + lx)*64) + ((((kk)*4+kg) ^ (lx&7))*8)]; \
} while (0)

#define MFMA16(accrow, A_, B_) do { \
  _Pragma("unroll") \
  for (int i_ = 0; i_ < 4; ++i_) \
  _Pragma("unroll") \
  for (int j_ = 0; j_ < 4; ++j_) \
    acc[(accrow)+i_][j_] = __builtin_amdgcn_mfma_f32_16x16x32_bf16(A_[i_], B_[j_], acc[(accrow)+i_][j_], 0, 0, 0); \
} while (0)

#define PHASE_MFMA(accrow, A_, B_) do { \
  __builtin_amdgcn_s_barrier(); \
  asm volatile("s_waitcnt lgkmcnt(0)" ::: "memory"); \
  __builtin_amdgcn_sched_barrier(0); \
  __builtin_amdgcn_s_setprio(1); \
  MFMA16(accrow, A_, B_); \
  __builtin_amdgcn_s_setprio(0); \
  __builtin_amdgcn_s_barrier(); \
} while (0)

__launch_bounds__(512)
__global__ void gemm_top2_kernel(const ushort* __restrict__ Aq, const ushort* __restrict__ Bq,
                                 const float* __restrict__ mnorm,
                                 float* __restrict__ pval, int* __restrict__ pidx,
                                 float* __restrict__ pm2) {
  __shared__ __align__(16) ushort lds[65536];   // 128 KiB: [2 buf][A 16384 | B 16384]
  const int t = threadIdx.x, lane = t & 63, wid = t >> 6;
  const int wr = wid >> 2, wc = wid & 3;        // 2 x 4 waves; per-wave C = 128 x 64
  const int lx = lane & 15, kg = lane >> 4;
  // XCD-chunked swizzle: 1024 blocks, 8 consecutive bids share rt (A-panel L2 reuse)
  int bid = ((int)blockIdx.x & 7) * 128 + ((int)blockIdx.x >> 3);
  const int rt = bid >> 3, ct = bid & 7;

  f32x4 acc[8][4];
#pragma unroll
  for (int i = 0; i < 8; ++i)
#pragma unroll
    for (int j = 0; j < 4; ++j) { acc[i][j][0] = 0.f; acc[i][j][1] = 0.f; acc[i][j][2] = 0.f; acc[i][j][3] = 0.f; }

  s16x8 af0[4], af1[4], bf[4];

  // prologue: stage K-tile 0 (akc=0, bkc=0) into buf 0
  STAGE_A(0, 0);
  STAGE_B(0, 0);

  for (int tt = 0; tt < 24; ++tt) {
    const int cur = tt & 1, nxt = cur ^ 1;
    const int t1 = tt + 1;
    const int akc1 = (t1 < 16) ? (t1 & 7) : (t1 - 8);
    const int bkc1 = t1 & 15;
    // iteration top: own prefetch for buf[cur] done, then align all waves
    asm volatile("s_waitcnt vmcnt(0)" ::: "memory");
    __builtin_amdgcn_s_barrier();
    // phase 0: B(kk0) + A(ib0,kk0) reads, prefetch A of tile t+1, MFMA quadrant
    READ_B(cur, 0, bf);
    READ_A(cur, 0, 0, af0);
    if (tt < 23) STAGE_A(nxt, akc1);
    PHASE_MFMA(0, af0, bf);
    // phase 1: A(ib1,kk0), prefetch B of tile t+1
    READ_A(cur, 1, 0, af1);
    if (tt < 23) STAGE_B(nxt, bkc1);
    PHASE_MFMA(4, af1, bf);
    // phase 2: B(kk1) + A(ib0,kk1)
    READ_B(cur, 1, bf);
    READ_A(cur, 0, 1, af0);
    PHASE_MFMA(0, af0, bf);
    // phase 3: A(ib1,kk1)
    READ_A(cur, 1, 1, af1);
    PHASE_MFMA(4, af1, bf);
  }

  __syncthreads();
  // epilogue: reuse LDS for cross-wave top-2 reduce
  float* rv1 = (float*)lds;            // [256][4]
  float* rv2 = rv1 + 1024;
  int*   ri1 = (int*)(rv2 + 1024);

  float mn[4];
#pragma unroll
  for (int j = 0; j < 4; ++j) mn[j] = mnorm[ct * 256 + wc * 64 + j * 16 + lx];
#pragma unroll
  for (int i = 0; i < 8; ++i)
#pragma unroll
    for (int reg = 0; reg < 4; ++reg) {
      float v1 = FLT_MAX, v2 = FLT_MAX; int i1 = 0;
#pragma unroll
      for (int j = 0; j < 4; ++j) {               // j ascending => k ascending
        float v = mn[j] - 2.f * acc[i][j][reg];
        int k = ct * 256 + wc * 64 + j * 16 + lx;
        if (v < v1) { v2 = v1; v1 = v; i1 = k; } else v2 = fminf(v2, v);
      }
#pragma unroll
      for (int msk = 1; msk < 16; msk <<= 1) {
        float o1 = __shfl_xor(v1, msk);
        int   oi = __shfl_xor(i1, msk);
        float o2 = __shfl_xor(v2, msk);
        top2_merge(v1, i1, v2, o1, oi, o2);
      }
      if (lx == 0) {
        int rowr = wr * 128 + i * 16 + kg * 4 + reg;
        rv1[rowr * 4 + wc] = v1; ri1[rowr * 4 + wc] = i1; rv2[rowr * 4 + wc] = v2;
      }
    }
  __syncthreads();
  if (t < 256) {
    float a1 = FLT_MAX, a2 = FLT_MAX; int ai = 0x7fffffff;
#pragma unroll
    for (int c = 0; c < 4; ++c)                    // wc ascending => k ascending
      top2_merge(a1, ai, a2, rv1[t * 4 + c], ri1[t * 4 + c], rv2[t * 4 + c]);
    size_t n = (size_t)rt * 256 + t;
    pval[n * 8 + ct] = a1;
    pidx[n * 8 + ct] = ai;
    pm2 [n * 8 + ct] = a2;
  }
}

// merge 8 col-tile partials per row; flag ambiguous; count + inertia for sure rows
__global__ void merge2_kernel(const float* __restrict__ pval, const int* __restrict__ pidx,
                              const float* __restrict__ pm2, const float* __restrict__ snorm,
                              int* __restrict__ bins, float* __restrict__ inertia,
                              int* __restrict__ counts,
                              int* __restrict__ flag_list, int* __restrict__ flag_count) {
  int n = blockIdx.x * 256 + threadIdx.x;
  float a1 = FLT_MAX, a2 = FLT_MAX; int ai = 0x7fffffff;
#pragma unroll
  for (int c = 0; c < 8; ++c)
    top2_merge(a1, ai, a2, pval[(size_t)n * 8 + c], pidx[(size_t)n * 8 + c], pm2[(size_t)n * 8 + c]);
  float r = 0.f;
  if (a2 - a1 <= MARGIN) {
    int idx = atomicAdd(flag_count, 1);
    flag_list[idx] = n;
  } else {
    bins[n] = ai;
    atomicAdd(&counts[ai], 1);
    r = sqrtf(fmaxf(snorm[n] + a1, 0.f));
  }
  for (int off = 32; off; off >>= 1) r += __shfl_down(r, off);
  if ((threadIdx.x & 63) == 0) atomicAdd(inertia, r);
}

// batched exact fp32 re-resolve: coalesced M reads, packed-u64 atomicMin argmin.
__launch_bounds__(256)
__global__ void cleanup_dist_kernel(const float* __restrict__ S, const float* __restrict__ M,
                                    const float* __restrict__ mnorm,
                                    const int* __restrict__ flag_list, const int* __restrict__ flag_count,
                                    unsigned long long* __restrict__ keys) {
  const int t = threadIdx.x, lane = t & 63, w = t >> 6;
  const int items = (*flag_count) * 8;
  for (int it = blockIdx.x; it < items; it += gridDim.x) {
    int fi = it >> 3, chunk = it & 7;
    int n = flag_list[fi];
    const float4* sp = (const float4*)(S + (size_t)n * D_DIM + lane * 8);
    float4 s0 = sp[0], s1 = sp[1];
    int kb = chunk * 256 + w * 64;
    unsigned long long bestkey = ~0ull;
    for (int ro = 0; ro < 8; ++ro) {
      float p[8];
#pragma unroll
      for (int rj = 0; rj < 8; ++rj) {
        const float4* mr = (const float4*)(M + (size_t)(kb + ro * 8 + rj) * D_DIM + lane * 8);
        float4 a = mr[0], b = mr[1];
        p[rj] = a.x*s0.x + a.y*s0.y + a.z*s0.z + a.w*s0.w
              + b.x*s1.x + b.y*s1.y + b.z*s1.z + b.w*s1.w;
      }
#pragma unroll
      for (int rj = 0; rj < 8; ++rj)
#pragma unroll
        for (int off = 1; off < 64; off <<= 1) p[rj] += __shfl_xor(p[rj], off);
#pragma unroll
      for (int rj = 0; rj < 8; ++rj) {
        int k = kb + ro * 8 + rj;
        float dist = mnorm[k] - 2.f * p[rj];
        unsigned u = __float_as_uint(dist);
        u = (u >> 31) ? ~u : (u | 0x80000000u);
        unsigned long long key = ((unsigned long long)u << 32) | (unsigned)k;
        bestkey = bestkey < key ? bestkey : key;
      }
    }
    if (lane == 0) atomicMin(keys + n, bestkey);
  }
}

__global__ void cleanup_resolve_kernel(const int* __restrict__ flag_list, const int* __restrict__ flag_count,
                                       const unsigned long long* __restrict__ keys,
                                       const float* __restrict__ snorm,
                                       int* __restrict__ bins, int* __restrict__ counts,
                                       float* __restrict__ inertia) {
  int cnt = *flag_count;
  int i = blockIdx.x * 256 + threadIdx.x;
  float r = 0.f;
  if (i < cnt) {
    int n = flag_list[i];
    unsigned long long key = keys[n];
    int k = (int)(unsigned)(key & 0xffffffffu);
    unsigned u = (unsigned)(key >> 32);
    u = (u >> 31) ? (u & 0x7fffffffu) : ~u;
    float dist = __uint_as_float(u);
    bins[n] = k;
    atomicAdd(&counts[k], 1);
    r = sqrtf(fmaxf(snorm[n] + dist, 0.f));
  }
  for (int off = 32; off; off >>= 1) r += __shfl_down(r, off);
  if ((threadIdx.x & 63) == 0) atomicAdd(inertia, r);
}

// exclusive prefix sum over 2048 counts (single block)
__global__ void prefix_kernel(const int* __restrict__ counts, int* __restrict__ starts,
                              int* __restrict__ cursor) {
  __shared__ int part[256];
  int t = threadIdx.x;
  int loc[8]; int s = 0;
#pragma unroll
  for (int i = 0; i < 8; ++i) { loc[i] = s; s += counts[t * 8 + i]; }
  part[t] = s;
  __syncthreads();
  for (int off = 1; off < 256; off <<= 1) {
    int v = (t >= off) ? part[t - off] : 0;
    __syncthreads();
    part[t] += v;
    __syncthreads();
  }
  int base = (t == 0) ? 0 : part[t - 1];
#pragma unroll
  for (int i = 0; i < 8; ++i) { starts[t * 8 + i] = base + loc[i]; cursor[t * 8 + i] = base + loc[i]; }
}

__global__ void fill_kernel(const int* __restrict__ bins, int* __restrict__ cursor,
                            int* __restrict__ bucket) {
  int n = blockIdx.x * 256 + threadIdx.x;
  int pos = atomicAdd(&cursor[bins[n]], 1);
  bucket[pos] = n;
}

// per-cluster gather of assigned samples + finalize new_means (no atomics)
__global__ void gather_finalize_kernel(const float* __restrict__ S, const float* __restrict__ M,
                                       const float* __restrict__ W,
                                       const int* __restrict__ starts, const int* __restrict__ counts,
                                       const int* __restrict__ bucket, float* __restrict__ out) {
  int k = blockIdx.x, t = threadIdx.x;
  int cnt = counts[k], s0 = starts[k];
  float acc0 = 0.f, acc1 = 0.f;
  for (int i = 0; i < cnt; ++i) {
    const float* row = S + (size_t)bucket[s0 + i] * D_DIM;
    acc0 += row[t];
    acc1 += row[t + 256];
  }
  float w = W[k];
  float nw = w + (float)cnt;
  float alpha = 1.f / ((nw == 0.f) ? 1.f : nw);
  size_t o = (size_t)k * D_DIM + t;
  float m0 = M[o], m1 = M[o + 256];
  out[o]       = (cnt == 0) ? m0 : (acc0 + m0 * w) * alpha;
  out[o + 256] = (cnt == 0) ? m1 : (acc1 + m1 * w) * alpha;
}

// ============================================================ FALLBACK PATH (round-2)

#define TM    128
#define BK2   32
#define SPLIT 2
#define KPER  (K_C / SPLIT)
#define NKT   (KPER / TM)
#define NDT   (D_DIM / BK2)

__global__ void row_norms_kernel(const float* __restrict__ S, const float* __restrict__ M,
                                 float* __restrict__ snorm, float* __restrict__ mnorm) {
  int row  = blockIdx.x * 4 + (threadIdx.x >> 6);
  int lane = threadIdx.x & 63;
  if (row >= N_S + K_C) return;
  const float* src;
  float* dst;
  if (row < N_S) { src = S + (size_t)row * D_DIM; dst = snorm + row; }
  else { int r = row - N_S; src = M + (size_t)r * D_DIM; dst = mnorm + r; }
  float4 v0 = *(const float4*)(src + lane * 4);
  float4 v1 = *(const float4*)(src + 256 + lane * 4);
  float s = v0.x*v0.x + v0.y*v0.y + v0.z*v0.z + v0.w*v0.w
          + v1.x*v1.x + v1.y*v1.y + v1.z*v1.z + v1.w*v1.w;
  for (int off = 32; off; off >>= 1) s += __shfl_down(s, off);
  if (lane == 0) *dst = s;
}

__launch_bounds__(256)
__global__ void dist_argmin_kernel(const float* __restrict__ S, const float* __restrict__ M,
                                   const float* __restrict__ mnorm,
                                   float* __restrict__ pval, int* __restrict__ pidx,
                                   float* __restrict__ pm2) {
  __shared__ ushort tiles[2][4][TM * BK2];
  __shared__ float sm1[TM * 2];
  __shared__ float sm2[TM * 2];
  __shared__ int   si1[TM * 2];
  const int t    = threadIdx.x;
  const int lane = t & 63, wid = t >> 6;
  const int wr   = wid >> 1, wc = wid & 1;
  const int lx   = lane & 15, kg = lane >> 4;
  const int stile = blockIdx.x >> 1, split = blockIdx.x & 1;
  const int srow0 = stile * TM;
  const int kcol0 = split * KPER;
  for (int i = t; i < TM * 2; i += 256) { sm1[i] = FLT_MAX; sm2[i] = FLT_MAX; si1[i] = 0; }
  float4 av[4], bv[4];
#define LOADREGS(dtoff) do { \
    const float* Ag = S + (size_t)srow0 * D_DIM + (dtoff); \
    const float* Bg = M + (size_t)kbase * D_DIM + (dtoff); \
    _Pragma("unroll") \
    for (int q = 0; q < 4; ++q) { \
      int id = t + q * 256; int r_ = id >> 3, c_ = (id & 7) * 4; \
      av[q] = *(const float4*)(Ag + (size_t)r_ * D_DIM + c_); \
      bv[q] = *(const float4*)(Bg + (size_t)r_ * D_DIM + c_); \
    } } while (0)
#define WRITETILE(buf) do { \
    _Pragma("unroll") \
    for (int q = 0; q < 4; ++q) { \
      int id = t + q * 256; int r_ = id >> 3, c_ = (id & 7) * 4; \
      ushort4 h4, l4; \
      cvt_hl(av[q].x, h4.x, l4.x); cvt_hl(av[q].y, h4.y, l4.y); \
      cvt_hl(av[q].z, h4.z, l4.z); cvt_hl(av[q].w, h4.w, l4.w); \
      *(ushort4*)&tiles[buf][0][r_ * BK2 + c_] = h4; \
      *(ushort4*)&tiles[buf][1][r_ * BK2 + c_] = l4; \
      cvt_hl(bv[q].x, h4.x, l4.x); cvt_hl(bv[q].y, h4.y, l4.y); \
      cvt_hl(bv[q].z, h4.z, l4.z); cvt_hl(bv[q].w, h4.w, l4.w); \
      *(ushort4*)&tiles[buf][2][r_ * BK2 + c_] = h4; \
      *(ushort4*)&tiles[buf][3][r_ * BK2 + c_] = l4; \
    } } while (0)
  for (int kt = 0; kt < NKT; ++kt) {
    const int kbase = kcol0 + kt * TM;
    f32x4 acc[4][4];
#pragma unroll
    for (int i = 0; i < 4; ++i)
#pragma unroll
      for (int j = 0; j < 4; ++j) { acc[i][j][0] = 0.f; acc[i][j][1] = 0.f; acc[i][j][2] = 0.f; acc[i][j][3] = 0.f; }
    float mn[4];
#pragma unroll
    for (int ni = 0; ni < 4; ++ni) mn[ni] = mnorm[kbase + wc * 64 + ni * 16 + lx];
    LOADREGS(0);
    WRITETILE(0);
    __syncthreads();
    for (int di = 0; di < NDT; ++di) {
      const int cur = di & 1;
      if (di + 1 < NDT) LOADREGS((di + 1) * BK2);
      {
        s16x8 ah[4], al[4], bh[4], bl[4];
#pragma unroll
        for (int i = 0; i < 4; ++i) {
          ah[i] = *(const s16x8*)&tiles[cur][0][(wr * 64 + i * 16 + lx) * BK2 + kg * 8];
          al[i] = *(const s16x8*)&tiles[cur][1][(wr * 64 + i * 16 + lx) * BK2 + kg * 8];
          bh[i] = *(const s16x8*)&tiles[cur][2][(wc * 64 + i * 16 + lx) * BK2 + kg * 8];
          bl[i] = *(const s16x8*)&tiles[cur][3][(wc * 64 + i * 16 + lx) * BK2 + kg * 8];
        }
#pragma unroll
        for (int i = 0; i < 4; ++i)
#pragma unroll
          for (int j = 0; j < 4; ++j) {
            acc[i][j] = __builtin_amdgcn_mfma_f32_16x16x32_bf16(ah[i], bh[j], acc[i][j], 0, 0, 0);
            acc[i][j] = __builtin_amdgcn_mfma_f32_16x16x32_bf16(ah[i], bl[j], acc[i][j], 0, 0, 0);
            acc[i][j] = __builtin_amdgcn_mfma_f32_16x16x32_bf16(al[i], bh[j], acc[i][j], 0, 0, 0);
          }
      }
      if (di + 1 < NDT) { WRITETILE(cur ^ 1); __syncthreads(); }
    }
#pragma unroll
    for (int mi = 0; mi < 4; ++mi)
#pragma unroll
      for (int r = 0; r < 4; ++r) {
        float v1 = FLT_MAX, v2 = FLT_MAX; int i1 = 0;
#pragma unroll
        for (int ni = 0; ni < 4; ++ni) {
          float v = mn[ni] - 2.f * acc[mi][ni][r];
          int k = kbase + wc * 64 + ni * 16 + lx;
          if (v < v1) { v2 = v1; v1 = v; i1 = k; } else { v2 = fminf(v2, v); }
        }
#pragma unroll
        for (int msk = 1; msk < 16; msk <<= 1) {
          float o1 = __shfl_xor(v1, msk);
          int   oi = __shfl_xor(i1, msk);
          float o2 = __shfl_xor(v2, msk);
          top2_merge(v1, i1, v2, o1, oi, o2);
        }
        if (lx == 0) {
          int row = wr * 64 + mi * 16 + kg * 4 + r;
          int s = row * 2 + wc;
          float a1 = sm1[s], a2 = sm2[s]; int ai = si1[s];
          top2_merge(a1, ai, a2, v1, i1, v2);
          sm1[s] = a1; sm2[s] = a2; si1[s] = ai;
        }
      }
  }
  __syncthreads();
  if (t < TM) {
    float a1 = sm1[t * 2], a2 = sm2[t * 2]; int ai = si1[t * 2];
    top2_merge(a1, ai, a2, sm1[t * 2 + 1], si1[t * 2 + 1], sm2[t * 2 + 1]);
    int n = srow0 + t;
    pval[n * SPLIT + split] = a1;
    pidx[n * SPLIT + split] = ai;
    pm2[n * SPLIT + split]  = a2;
  }
#undef LOADREGS
#undef WRITETILE
}

__global__ void merge_bins_kernel(const float* __restrict__ pval, const int* __restrict__ pidx,
                                  const float* __restrict__ pm2, const float* __restrict__ snorm,
                                  int* __restrict__ bins, float* __restrict__ inertia,
                                  int* __restrict__ flag_list, int* __restrict__ flag_count) {
  int n = blockIdx.x * 256 + threadIdx.x;
  float a1 = pval[n * SPLIT], a2 = pm2[n * SPLIT]; int ai = pidx[n * SPLIT];
  top2_merge(a1, ai, a2, pval[n * SPLIT + 1], pidx[n * SPLIT + 1], pm2[n * SPLIT + 1]);
  float r = 0.f;
  if (a2 - a1 <= MARGIN) {
    int idx = atomicAdd(flag_count, 1);
    flag_list[idx] = n;
  } else {
    bins[n] = ai;
    r = sqrtf(fmaxf(snorm[n] + a1, 0.f));
  }
  for (int off = 32; off; off >>= 1) r += __shfl_down(r, off);
  if ((threadIdx.x & 63) == 0) atomicAdd(inertia, r);
}

__launch_bounds__(256)
__global__ void cleanup_kernel(const float* __restrict__ S, const float* __restrict__ M,
                               const float* __restrict__ snorm, const float* __restrict__ mnorm,
                               const int* __restrict__ flag_list, const int* __restrict__ flag_count,
                               int* __restrict__ bins, float* __restrict__ inertia) {
  __shared__ float sS[D_DIM];
  __shared__ float wv[4];
  __shared__ int   wk[4];
  const int t = threadIdx.x, lane = t & 63, wid = t >> 6;
  const int cnt = *flag_count;
  for (int fi = blockIdx.x; fi < cnt; fi += gridDim.x) {
    int n = flag_list[fi];
    __syncthreads();
    for (int i = t; i < D_DIM; i += 256) sS[i] = S[(size_t)n * D_DIM + i];
    __syncthreads();
    float best = FLT_MAX; int bk = 0;
    for (int k = wid; k < K_C; k += 4) {
      const float* mr = M + (size_t)k * D_DIM;
      float4 m0 = *(const float4*)(mr + lane * 8);
      float4 m1 = *(const float4*)(mr + lane * 8 + 4);
      float4 s0 = *(const float4*)(sS + lane * 8);
      float4 s1 = *(const float4*)(sS + lane * 8 + 4);
      float p = m0.x*s0.x + m0.y*s0.y + m0.z*s0.z + m0.w*s0.w
              + m1.x*s1.x + m1.y*s1.y + m1.z*s1.z + m1.w*s1.w;
      for (int msk = 1; msk < 64; msk <<= 1) p += __shfl_xor(p, msk);
      float dist = mnorm[k] - 2.f * p;
      if (dist < best) { best = dist; bk = k; }
    }
    if (lane == 0) { wv[wid] = best; wk[wid] = bk; }
    __syncthreads();
    if (t == 0) {
      float b = wv[0]; int bi = wk[0];
      for (int w = 1; w < 4; ++w)
        if (wv[w] < b || (wv[w] == b && wk[w] < bi)) { b = wv[w]; bi = wk[w]; }
      bins[n] = bi;
      atomicAdd(inertia, sqrtf(fmaxf(snorm[n] + b, 0.f)));
    }
  }
}

__global__ void scatter_kernel(const float* __restrict__ S, const int* __restrict__ bins,
                               float* __restrict__ csum, float* __restrict__ counts) {
  int w    = (blockIdx.x * 256 + threadIdx.x) >> 6;
  int lane = threadIdx.x & 63;
  if (w >= N_S) return;
  int b = bins[w];
  const float* src = S + (size_t)w * D_DIM;
  float* dst = csum + (size_t)b * D_DIM;
#pragma unroll
  for (int c = 0; c < D_DIM; c += 64) atomicAdd(dst + c + lane, src[c + lane]);
  if (lane == 0) atomicAdd(counts + b, 1.0f);
}

__global__ void finalize_kernel(const float* __restrict__ M, const float* __restrict__ W,
                                const float* __restrict__ counts, float* __restrict__ out) {
  int idx = blockIdx.x * 256 + threadIdx.x;
  int k = idx >> 9;
  float cnt = counts[k];
  float w   = W[k];
  float nw  = w + cnt;
  float alpha = 1.f / ((nw == 0.f) ? 1.f : nw);
  float m = M[idx];
  float v = (out[idx] + m * w) * alpha;
  out[idx] = (cnt == 0.f) ? m : v;
}

// ================================================================= launcher

extern "C" void kernel_launch(void* const* d_in, const int* in_sizes, int n_in,
                              void* d_out, int out_size, void* d_ws, size_t ws_size,
                              hipStream_t stream) {
  const float* S = (const float*)d_in[0];
  const float* M = (const float*)d_in[1];
  const float* W = (const float*)d_in[2];
  float* out = (float*)d_out;
  char* ws = (char*)d_ws;

  const size_t oA  = 0;                                // A' 64 MiB
  const size_t oB  = oA  + (size_t)N_S * 1024 * 2;     // B' 4 MiB
  const size_t oPV = oB  + (size_t)K_C * 1024 * 2;     // pval [N][8]
  const size_t oPM = oPV + (size_t)N_S * 8 * 4;
  const size_t oPI = oPM + (size_t)N_S * 8 * 4;
  const size_t oSN = oPI + (size_t)N_S * 8 * 4;        // snorm
  const size_t oMN = oSN + (size_t)N_S * 4;            // mnorm
  const size_t oBI = oMN + (size_t)K_C * 4;            // bins
  const size_t oCN = oBI + (size_t)N_S * 4;            // counts (int)
  const size_t oST = oCN + (size_t)K_C * 4;            // starts
  const size_t oCU = oST + (size_t)K_C * 4;            // cursor
  const size_t oBK = oCU + (size_t)K_C * 4;            // bucket
  const size_t oFC = oBK + (size_t)N_S * 4;            // flag_count
  const size_t oFL = oFC + 64;                         // flag_list
  const size_t oKY = oFL + (size_t)N_S * 4;            // keys (u64, 8B-aligned)
  const size_t NEED = oKY + (size_t)N_S * 8;

  if (ws_size >= NEED) {
    ushort* Aq = (ushort*)(ws + oA);
    ushort* Bq = (ushort*)(ws + oB);
    float* pval = (float*)(ws + oPV);
    float* pm2  = (float*)(ws + oPM);
    int*   pidx = (int*)(ws + oPI);
    float* snorm = (float*)(ws + oSN);
    float* mnorm = (float*)(ws + oMN);
    int* bins   = (int*)(ws + oBI);
    int* counts = (int*)(ws + oCN);
    int* starts = (int*)(ws + oST);
    int* cursor = (int*)(ws + oCU);
    int* bucket = (int*)(ws + oBK);
    int* flag_count = (int*)(ws + oFC);
    int* flag_list  = (int*)(ws + oFL);
    unsigned long long* keys = (unsigned long long*)(ws + oKY);

    hipMemsetAsync(counts, 0, (size_t)K_C * 4, stream);
    hipMemsetAsync(flag_count, 0, 64, stream);
    hipMemsetAsync(out + KD, 0, sizeof(float), stream);
    hipMemsetAsync(keys, 0xFF, (size_t)N_S * 8, stream);

    preconvert_kernel<<<(N_S + K_C) / 4, 256, 0, stream>>>(S, M, Aq, Bq, snorm, mnorm);
    gemm_top2_kernel<<<1024, 512, 0, stream>>>(Aq, Bq, mnorm, pval, pidx, pm2);
    merge2_kernel<<<N_S / 256, 256, 0, stream>>>(pval, pidx, pm2, snorm, bins, out + KD,
                                                 counts, flag_list, flag_count);
    cleanup_dist_kernel<<<1024, 256, 0, stream>>>(S, M, mnorm, flag_list, flag_count, keys);
    cleanup_resolve_kernel<<<N_S / 256, 256, 0, stream>>>(flag_list, flag_count, keys, snorm,
                                                          bins, counts, out + KD);
    prefix_kernel<<<1, 256, 0, stream>>>(counts, starts, cursor);
    fill_kernel<<<N_S / 256, 256, 0, stream>>>(bins, cursor, bucket);
    gather_finalize_kernel<<<K_C, 256, 0, stream>>>(S, M, W, starts, counts, bucket, out);
  } else {
    float* mnorm     = (float*)ws;
    float* snorm     = mnorm + K_C;
    int*   bins      = (int*)(snorm + N_S);
    float* counts    = (float*)(bins + N_S);
    float* pval      = counts + K_C;
    int*   pidx      = (int*)(pval + (size_t)N_S * 2);
    float* pm2       = (float*)(pidx + (size_t)N_S * 2);
    int*   flag_count= (int*)(pm2 + (size_t)N_S * 2);
    int*   flag_list = flag_count + 16;

    hipMemsetAsync(d_out, 0, (size_t)(KD + 1) * sizeof(float), stream);
    hipMemsetAsync(counts, 0, K_C * sizeof(float), stream);
    hipMemsetAsync(flag_count, 0, sizeof(int), stream);

    row_norms_kernel<<<(N_S + K_C) / 4, 256, 0, stream>>>(S, M, snorm, mnorm);
    dist_argmin_kernel<<<(N_S / TM) * SPLIT, 256, 0, stream>>>(S, M, mnorm, pval, pidx, pm2);
    merge_bins_kernel<<<N_S / 256, 256, 0, stream>>>(pval, pidx, pm2, snorm, bins, out + KD,
                                                     flag_list, flag_count);
    cleanup_kernel<<<1024, 256, 0, stream>>>(S, M, snorm, mnorm, flag_list, flag_count,
                                             bins, out + KD);
    scatter_kernel<<<N_S / 4, 256, 0, stream>>>(S, bins, out, counts);
    finalize_kernel<<<KD / 256, 256, 0, stream>>>(M, W, counts, out);
  }
}